// Round 10
// baseline (592.107 us; speedup 1.0000x reference)
//
#include <hip/hip_runtime.h>

typedef _Float16 f16;
typedef f16  f16x8 __attribute__((ext_vector_type(8)));
typedef float f32x4 __attribute__((ext_vector_type(4)));

#define S3 3145728LL   // per-batch per-component elems (12*256*16*64 = 4096*768)

__device__ __forceinline__ f32x4 mm(f16x8 a, f16x8 b, f32x4 c) {
  return __builtin_amdgcn_mfma_f32_16x16x32_f16(a, b, c, 0, 0, 0);
}
__device__ __forceinline__ void BAR() { asm volatile("s_barrier" ::: "memory"); }

// epilogue LDS swizzle: f16 index for (t, col) in the full [256][256] tile
__device__ __forceinline__ int esw(int t, int col) {
  return t * 256 + ((((col >> 3) ^ ((t ^ (t >> 3)) & 7)) << 3) | (col & 7));
}

// ---------------- transpose + fp32->fp16 convert: out[Cc][R] = in[R][Cc] ----
__global__ void cvt_T_kernel(const float* __restrict__ in, f16* __restrict__ out,
                             int R, int Cc) {
  __shared__ float tile[32][33];
  int tc = blockIdx.x, tr = blockIdx.y;
  int lr = threadIdx.x & 31, lw = threadIdx.x >> 5;
  int c0 = tc * 32, r0 = tr * 32;
#pragma unroll
  for (int i = 0; i < 4; i++)
    tile[lw + 8 * i][lr] = in[(size_t)(r0 + lw + 8 * i) * Cc + c0 + lr];
  __syncthreads();
#pragma unroll
  for (int i = 0; i < 4; i++)
    out[(size_t)(c0 + lw + 8 * i) * R + r0 + lr] = (f16)tile[lr][lw + 8 * i];
}

// ---------------- x fp32 -> f16 (NT reads: x is never re-read) -------------
__global__ void cvt_x_kernel(const float* __restrict__ in, f16* __restrict__ out) {
  size_t i = ((size_t)blockIdx.x * 256 + threadIdx.x) * 8;
  f32x4 a = __builtin_nontemporal_load((const f32x4*)(in + i));
  f32x4 b = __builtin_nontemporal_load((const f32x4*)(in + i + 4));
  f16x8 o;
#pragma unroll
  for (int j = 0; j < 4; j++) { o[j] = (f16)a[j]; o[4 + j] = (f16)b[j]; }
  *(f16x8*)(out + i) = o;
}

// ---------------- QKV GEMM: 256x256 tile, BK=64, 2-phase pipelined ----------
#define STG_A(c, q, kt) __builtin_amdgcn_global_load_lds( \
    (const __attribute__((address_space(1))) void*)(aSrc + (size_t)(q) * 49152 + (size_t)(kt) * 64), \
    (__attribute__((address_space(3))) void*)(lds + (c) * 32768 + (q) * 4096 + wave * 512), 16, 0, 0)
#define STG_B(c, q, kt) __builtin_amdgcn_global_load_lds( \
    (const __attribute__((address_space(1))) void*)(bSrc + (size_t)(q) * 49152 + (size_t)(kt) * 64), \
    (__attribute__((address_space(3))) void*)(lds + 16384 + (c) * 32768 + (q) * 4096 + wave * 512), 16, 0, 0)

// K-loop: 2 merged phases per K-tile. NOTE: no forced lgkmcnt(0) — the
// ds_reads are compiler-visible, so hipcc emits fine-grained lgkmcnt(N)
// letting the first MFMAs overlap the remaining ds_read drain (the explicit
// drain was serializing the LDS burst against the MFMA burst).
// vmcnt invariant per tile end: <=4 outstanding (tile t+2's) => tile t+1 landed.
#define GEMM_K_LOOP(NT)                                                        \
  f16x8 af[4][2], ag[4][2], bf[2][2], bg[2][2];                                \
  _Pragma("unroll 2")                                                          \
  for (int t = 0; t < (NT); ++t) {                                             \
    int c = t & 1, nb = c ^ 1;                                                 \
    const char* ab = (const char*)lds + c * 65536;                             \
    const char* bb = ab + 32768;                                               \
    int rA = wr * 128 + l16;                                                   \
    int rB = wc * 64 + l16;                                                    \
    _Pragma("unroll")                                                          \
    for (int mf = 0; mf < 4; mf++) {                                           \
      af[mf][0] = *(const f16x8*)(ab + (rA + mf * 16) * 128 + cb0);            \
      af[mf][1] = *(const f16x8*)(ab + (rA + mf * 16) * 128 + cb1);            \
    }                                                                          \
    _Pragma("unroll")                                                          \
    for (int nf = 0; nf < 2; nf++) {                                           \
      bf[nf][0] = *(const f16x8*)(bb + (rB + nf * 16) * 128 + cb0);            \
      bf[nf][1] = *(const f16x8*)(bb + (rB + nf * 16) * 128 + cb1);            \
      bg[nf][0] = *(const f16x8*)(bb + (rB + 32 + nf * 16) * 128 + cb0);       \
      bg[nf][1] = *(const f16x8*)(bb + (rB + 32 + nf * 16) * 128 + cb1);       \
    }                                                                          \
    if (t < (NT) - 1) {                                                        \
      STG_B(nb, 2, t + 1); STG_B(nb, 3, t + 1);                                \
      STG_A(nb, 0, t + 1); STG_A(nb, 2, t + 1);                                \
    }                                                                          \
    BAR();                                                                     \
    __builtin_amdgcn_s_setprio(1);                                             \
    _Pragma("unroll")                                                          \
    for (int ks = 0; ks < 2; ks++)                                             \
      _Pragma("unroll")                                                        \
      for (int mf = 0; mf < 4; mf++)                                           \
        _Pragma("unroll")                                                      \
        for (int nf = 0; nf < 2; nf++) {                                       \
          acc[mf][nf]     = mm(af[mf][ks], bf[nf][ks], acc[mf][nf]);           \
          acc[mf][2 + nf] = mm(af[mf][ks], bg[nf][ks], acc[mf][2 + nf]);       \
        }                                                                      \
    __builtin_amdgcn_s_setprio(0);                                             \
    BAR();                                                                     \
    _Pragma("unroll")                                                          \
    for (int mf = 0; mf < 4; mf++) {                                           \
      ag[mf][0] = *(const f16x8*)(ab + (rA + 64 + mf * 16) * 128 + cb0);       \
      ag[mf][1] = *(const f16x8*)(ab + (rA + 64 + mf * 16) * 128 + cb1);       \
    }                                                                          \
    if (t < (NT) - 2) {                                                        \
      STG_A(c, 1, t + 2); STG_A(c, 3, t + 2);                                  \
      STG_B(c, 0, t + 2); STG_B(c, 1, t + 2);                                  \
    }                                                                          \
    BAR();                                                                     \
    __builtin_amdgcn_s_setprio(1);                                             \
    _Pragma("unroll")                                                          \
    for (int ks = 0; ks < 2; ks++)                                             \
      _Pragma("unroll")                                                        \
      for (int mf = 0; mf < 4; mf++)                                           \
        _Pragma("unroll")                                                      \
        for (int nf = 0; nf < 2; nf++) {                                       \
          acc[4 + mf][nf]     = mm(ag[mf][ks], bf[nf][ks], acc[4 + mf][nf]);   \
          acc[4 + mf][2 + nf] = mm(ag[mf][ks], bg[nf][ks], acc[4 + mf][2 + nf]);\
        }                                                                      \
    __builtin_amdgcn_s_setprio(0);                                             \
    if (t < (NT) - 2) asm volatile("s_waitcnt vmcnt(4)" ::: "memory");         \
    else              asm volatile("s_waitcnt vmcnt(0)" ::: "memory");         \
    BAR();                                                                     \
  }

#define GEMM_PROLOGUE()                                                        \
  STG_A(0, 0, 0); STG_A(0, 1, 0); STG_A(0, 2, 0); STG_A(0, 3, 0);              \
  STG_B(0, 0, 0); STG_B(0, 1, 0); STG_B(0, 2, 0); STG_B(0, 3, 0);              \
  STG_A(1, 1, 1); STG_A(1, 3, 1);                                              \
  STG_B(1, 0, 1); STG_B(1, 1, 1);                                              \
  asm volatile("s_waitcnt vmcnt(4)" ::: "memory");                             \
  BAR();

__global__ __launch_bounds__(512, 2) void gemm_qkv8(
    const f16* __restrict__ A, const f16* __restrict__ Bt,
    f16* __restrict__ area, long long cstr_) {
  __shared__ f16 lds[65536];   // K-loop: 2x(A 32KB|B 32KB); epilogue: full C-tile
  size_t cstr = (size_t)cstr_;
  int id  = blockIdx.x;
  int cpx = gridDim.x >> 3;
  int id2 = (id & 7) * cpx + (id >> 3);       // XCD swizzle (grid % 8 == 0)
  int sr = id2 / 144, rr = id2 % 144;
  int bm = sr * 8 + (rr & 7), bn = rr >> 3;   // bm 0..G*16-1, bn 0..17

  int tid = threadIdx.x;
  int wave = tid >> 6, lane = tid & 63;
  int l16 = lane & 15, lq = lane >> 4;
  int wr = wave >> 2, wc = wave & 3;          // 2 x 4 wave grid
  int sx  = (l16 & 7) << 4;                   // read-side XOR swizzle (bytes)
  int cb0 = (lq * 16) ^ sx;
  int cb1 = (64 + lq * 16) ^ sx;

  // pre-swizzled global sources (involution: col granule ^= (row&7))
  int scol = ((tid & 7) ^ ((tid >> 3) & 7)) << 3;   // f16 elems
  const f16* aSrc = A  + (size_t)(bm * 256 + (tid >> 3)) * 768 + scol;
  const f16* bSrc = Bt + (size_t)(bn * 256 + (tid >> 3)) * 768 + scol;

  f32x4 zz = {0.f, 0.f, 0.f, 0.f};
  f32x4 acc[8][4];
#pragma unroll
  for (int m = 0; m < 8; m++)
#pragma unroll
    for (int n = 0; n < 4; n++) acc[m][n] = zz;

  GEMM_PROLOGUE();
  GEMM_K_LOOP(12);

  // ---- single-pass full-tile LDS epilogue: all stores 1KB-contiguous/instr --
  // bn-tile lies in ONE component s = bn/3. Layouts:
  //  qc/kc [h][n][c][d]; qs/ks [h][c][n][d]; vc [h][n][d][c];
  //  vs BLOCKED [h][c][nb][d][nl16] (nb = n>>4 = bm&15, block-private).
  int s  = bn / 3;
  int h0 = (bn % 3) * 4;
  size_t comp;
  if (s == 0) comp = 0; else if (s == 1) comp = 1; else if (s == 2) comp = 3;
  else if (s == 3) comp = 4; else if (s == 4) comp = 2; else comp = 5;
  int g = (bm * 256) >> 12;
  size_t base = comp * cstr + (size_t)g * S3;
  int tok0 = (bm * 256) & 4095;
  int n0   = tok0 >> 4;          // multiple of 16
  int nbv  = n0 >> 4;

  __syncthreads();
#pragma unroll
  for (int mi = 0; mi < 8; mi++)
#pragma unroll
    for (int ni = 0; ni < 4; ni++)
#pragma unroll
      for (int r = 0; r < 4; r++) {
        int t = wr * 128 + (mi >> 2) * 64 + (mi & 3) * 16 + lq * 4 + r;
        int col = wc * 64 + ni * 16 + l16;
        lds[esw(t, col)] = (f16)acc[mi][ni][r];
      }
  __syncthreads();

  // 64 units of 2KB (hl 0..3 x j16 0..15), 8 per wave, 2 x 1KB instrs each.
#pragma unroll
  for (int i = 0; i < 8; i++) {
    int u = wave * 8 + i;
    int hl = u >> 4, j16 = u & 15;
    int h  = h0 + hl;
#pragma unroll
    for (int half = 0; half < 2; half++) {
      int e0 = half * 512 + lane * 8;
      f16x8 v;
      size_t dst;
      if (s < 2) {            // qc/kc: unit (hl, nloc=j16); e = c*64 + d
        int c = e0 >> 6, d0 = e0 & 63;
        v = *(const f16x8*)&lds[esw(j16 * 16 + c, hl * 64 + d0)];
        dst = base + (size_t)h * 262144 + (size_t)(n0 + j16) * 1024 + e0;
      } else if (s < 4) {     // qs/ks: unit (hl, c=j16); e = nloc*64 + d
        int nl = e0 >> 6, d0 = e0 & 63;
        v = *(const f16x8*)&lds[esw(nl * 16 + j16, hl * 64 + d0)];
        dst = base + (size_t)(h * 16 + j16) * 16384 + (size_t)n0 * 64 + e0;
      } else if (s == 4) {    // vc: unit (hl, nloc=j16); e = d*16 + c
        int d0 = e0 >> 4, cb = e0 & 15;
#pragma unroll
        for (int j = 0; j < 8; j++)
          v[j] = lds[esw(j16 * 16 + cb + j, hl * 64 + d0)];
        dst = base + (size_t)(h * 256 + n0 + j16) * 1024 + e0;
      } else {                // vs: unit (hl, c=j16); e = d*16 + nl
        int d0 = e0 >> 4, nlb = e0 & 15;
#pragma unroll
        for (int j = 0; j < 8; j++)
          v[j] = lds[esw((nlb + j) * 16 + j16, hl * 64 + d0)];
        dst = base + ((size_t)(h * 16 + j16) * 16 + nbv) * 1024 + e0;
      }
      __builtin_nontemporal_store(v, (f16x8*)&area[dst]);
    }
  }
}

// ---------------- proj GEMM: 256x256 tile, 2-phase, out = A*wpt^T + bias ----
__global__ __launch_bounds__(512, 2) void gemm_proj8(
    const f16* __restrict__ A,       // prod [G*4096][768]
    const f16* __restrict__ Bt,      // wpt [768][768]
    const float* __restrict__ bias, float* __restrict__ Cout) {
  __shared__ f16 lds[65536];
  int id  = blockIdx.x;
  int cpx = gridDim.x >> 3;
  int id2 = (id & 7) * cpx + (id >> 3);       // grid = G*48, %8==0
  int sr = id2 / 24, rr = id2 % 24;
  int bm = sr * 8 + (rr & 7), bn = rr >> 3;   // bm 0..G*16-1, bn 0..2

  int tid = threadIdx.x;
  int wave = tid >> 6, lane = tid & 63;
  int l16 = lane & 15, lq = lane >> 4;
  int wr = wave >> 2, wc = wave & 3;
  int sx  = (l16 & 7) << 4;
  int cb0 = (lq * 16) ^ sx;
  int cb1 = (64 + lq * 16) ^ sx;

  int scol = ((tid & 7) ^ ((tid >> 3) & 7)) << 3;
  const f16* aSrc = A  + (size_t)(bm * 256 + (tid >> 3)) * 768 + scol;
  const f16* bSrc = Bt + (size_t)(bn * 256 + (tid >> 3)) * 768 + scol;

  f32x4 zz = {0.f, 0.f, 0.f, 0.f};
  f32x4 acc[8][4];
#pragma unroll
  for (int m = 0; m < 8; m++)
#pragma unroll
    for (int n = 0; n < 4; n++) acc[m][n] = zz;

  GEMM_PROLOGUE();
  GEMM_K_LOOP(12);

  // direct fp32 epilogue with bias (NT: output never re-read)
#pragma unroll
  for (int ni = 0; ni < 4; ni++) {
    int col = bn * 256 + wc * 64 + ni * 16 + l16;
    float bb = bias[col];
#pragma unroll
    for (int mi = 0; mi < 8; mi++) {
#pragma unroll
      for (int r = 0; r < 4; r++) {
        int row = bm * 256 + wr * 128 + (mi >> 2) * 64 + (mi & 3) * 16 + lq * 4 + r;
        __builtin_nontemporal_store(acc[mi][ni][r] + bb,
                                    &Cout[(size_t)row * 768 + col]);
      }
    }
  }
}

// ---------------- spatial attention: per (g,h,c), flash over N=256 ----------
__global__ __launch_bounds__(512) void attn_spat_kernel(f16* __restrict__ area,
                                                        long long cstr_) {
  size_t cstr = (size_t)cstr_;
  int blk = blockIdx.x;
  int g = blk / 192, rem = blk % 192;
  int h = rem >> 4, c = rem & 15;
  size_t goff = (size_t)g * S3;
  const f16* qs = area + 3 * cstr + goff + (size_t)((h * 16 + c) * 256) * 64;
  const f16* ks = area + 4 * cstr + goff + (size_t)((h * 16 + c) * 256) * 64;
  const f16* vsb = area + 5 * cstr + goff + (size_t)(h * 16 + c) * 16384; // blocked [nb][d][nl]
  f16* xs = area + 6 * cstr + goff + (size_t)((h * 16 + c) * 256) * 64;

  int wave = threadIdx.x >> 6, lane = threadIdx.x & 63;
  int l16 = lane & 15, lq = lane >> 4;
  __shared__ f16 plds[8][32][40];

  f32x4 zz = {0.f, 0.f, 0.f, 0.f};
  f16x8 aq[2][2];
#pragma unroll
  for (int m = 0; m < 2; m++)
#pragma unroll
    for (int kd = 0; kd < 2; kd++)
      aq[m][kd] = *(const f16x8*)&qs[(size_t)(wave * 32 + m * 16 + l16) * 64 + kd * 32 + lq * 8];

  f32x4 o[2][4];
  float mrow[2][4], lrow[2][4];
#pragma unroll
  for (int m = 0; m < 2; m++) {
#pragma unroll
    for (int n = 0; n < 4; n++) o[m][n] = zz;
#pragma unroll
    for (int r = 0; r < 4; r++) { mrow[m][r] = -1e30f; lrow[m][r] = 0.f; }
  }

  for (int kc = 0; kc < 8; kc++) {
    int k0 = kc * 32;
    f16x8 bk00 = *(const f16x8*)&ks[(size_t)(k0 + l16) * 64 + lq * 8];
    f16x8 bk01 = *(const f16x8*)&ks[(size_t)(k0 + l16) * 64 + 32 + lq * 8];
    f16x8 bk10 = *(const f16x8*)&ks[(size_t)(k0 + 16 + l16) * 64 + lq * 8];
    f16x8 bk11 = *(const f16x8*)&ks[(size_t)(k0 + 16 + l16) * 64 + 32 + lq * 8];
    f32x4 st[2][2];
#pragma unroll
    for (int m = 0; m < 2; m++) {
      st[m][0] = mm(aq[m][1], bk01, mm(aq[m][0], bk00, zz));
      st[m][1] = mm(aq[m][1], bk11, mm(aq[m][0], bk10, zz));
    }
#pragma unroll
    for (int m = 0; m < 2; m++) {
#pragma unroll
      for (int r = 0; r < 4; r++) {
        float s0 = st[m][0][r] * 0.125f, s1 = st[m][1][r] * 0.125f;
        float t = fmaxf(s0, s1);
        t = fmaxf(t, __shfl_xor(t, 1));
        t = fmaxf(t, __shfl_xor(t, 2));
        t = fmaxf(t, __shfl_xor(t, 4));
        t = fmaxf(t, __shfl_xor(t, 8));
        float mold = mrow[m][r];
        float mnew = fmaxf(mold, t);
        float fac  = __expf(mold - mnew);
        mrow[m][r] = mnew;
        float p0 = __expf(s0 - mnew), p1 = __expf(s1 - mnew);
        lrow[m][r] = lrow[m][r] * fac + p0 + p1;
        o[m][0][r] *= fac; o[m][1][r] *= fac; o[m][2][r] *= fac; o[m][3][r] *= fac;
        int prow = m * 16 + lq * 4 + r;
        plds[wave][prow][l16]      = (f16)p0;
        plds[wave][prow][16 + l16] = (f16)p1;
      }
    }
    f16x8 ap0 = *(const f16x8*)&plds[wave][l16][lq * 8];
    f16x8 ap1 = *(const f16x8*)&plds[wave][16 + l16][lq * 8];
    int nb = (k0 >> 4) + (lq >> 1);
    int nl0 = (lq & 1) * 8;
#pragma unroll
    for (int n = 0; n < 4; n++) {
      f16x8 bv = *(const f16x8*)&vsb[nb * 1024 + (n * 16 + l16) * 16 + nl0];
      o[0][n] = mm(ap0, bv, o[0][n]);
      o[1][n] = mm(ap1, bv, o[1][n]);
    }
  }
#pragma unroll
  for (int m = 0; m < 2; m++)
#pragma unroll
    for (int r = 0; r < 4; r++) {
      float l = lrow[m][r];
      l += __shfl_xor(l, 1);
      l += __shfl_xor(l, 2);
      l += __shfl_xor(l, 4);
      l += __shfl_xor(l, 8);
      lrow[m][r] = 1.0f / l;
    }
#pragma unroll
  for (int m = 0; m < 2; m++)
#pragma unroll
    for (int n = 0; n < 4; n++)
#pragma unroll
      for (int r = 0; r < 4; r++) {
        int row = wave * 32 + m * 16 + lq * 4 + r;
        xs[(size_t)row * 64 + n * 16 + l16] = (f16)(o[m][n][r] * lrow[m][r]);
      }
}

// ---------------- channel attention + combine: per (g,n), 12 heads ----------
__global__ __launch_bounds__(256) void attn_chan_kernel(f16* __restrict__ area,
                                                        long long cstr_) {
  size_t cstr = (size_t)cstr_;
  int blk = blockIdx.x;
  int g = blk >> 8, n = blk & 255;
  size_t goff = (size_t)g * S3;
  int wave = threadIdx.x >> 6, lane = threadIdx.x & 63;
  int l16 = lane & 15, lq = lane >> 4;
  __shared__ f16 plds[4][16][40];
  if (lane < 16) {
#pragma unroll
    for (int j = 0; j < 16; j++) plds[wave][lane][16 + j] = (f16)0.f;  // zero K-pad
  }
  const f16* xs = area + 6 * cstr + goff;
  f16* prod = area + 7 * cstr + goff;
  f32x4 zz = {0.f, 0.f, 0.f, 0.f};
  for (int hi = 0; hi < 3; hi++) {
    int h = wave + hi * 4;
    const f16* q = area + 0 * cstr + goff + (size_t)((h * 256 + n) * 16) * 64;
    const f16* k = area + 1 * cstr + goff + (size_t)((h * 256 + n) * 16) * 64;
    const f16* v = area + 2 * cstr + goff + (size_t)((h * 256 + n) * 64) * 16; // [d][c]
    f16x8 a0 = *(const f16x8*)&q[l16 * 64 + lq * 8];
    f16x8 a1 = *(const f16x8*)&q[l16 * 64 + 32 + lq * 8];
    f16x8 b0 = *(const f16x8*)&k[l16 * 64 + lq * 8];
    f16x8 b1 = *(const f16x8*)&k[l16 * 64 + 32 + lq * 8];
    f32x4 s = mm(a1, b1, mm(a0, b0, zz));
    float p[4];
#pragma unroll
    for (int r = 0; r < 4; r++) {
      float t = s[r] * 0.125f;
      float mx = t;
      mx = fmaxf(mx, __shfl_xor(mx, 1));
      mx = fmaxf(mx, __shfl_xor(mx, 2));
      mx = fmaxf(mx, __shfl_xor(mx, 4));
      mx = fmaxf(mx, __shfl_xor(mx, 8));
      float e = __expf(t - mx);
      float sum = e;
      sum += __shfl_xor(sum, 1);
      sum += __shfl_xor(sum, 2);
      sum += __shfl_xor(sum, 4);
      sum += __shfl_xor(sum, 8);
      p[r] = e / sum;
    }
#pragma unroll
    for (int r = 0; r < 4; r++)
      plds[wave][lq * 4 + r][l16] = (f16)p[r];
    f16x8 ap = *(const f16x8*)&plds[wave][l16][lq * 8]; // k>=16 are zeros
#pragma unroll
    for (int nt = 0; nt < 4; nt++) {
      f16x8 bv = *(const f16x8*)&v[(nt * 16 + l16) * 16 + lq * 8];
      f32x4 o = mm(ap, bv, zz);
#pragma unroll
      for (int r = 0; r < 4; r++) {
        int cq = lq * 4 + r, d = nt * 16 + l16;
        float xsv = (float)xs[(size_t)((h * 16 + cq) * 256 + n) * 64 + d];
        prod[(size_t)n * 12288 + h * 1024 + cq * 64 + d] = (f16)(o[r] * xsv);
      }
    }
  }
}

// ---------------- host ------------------------------------------------------
extern "C" void kernel_launch(void* const* d_in, const int* in_sizes, int n_in,
                              void* d_out, int out_size, void* d_ws, size_t ws_size,
                              hipStream_t stream) {
  const float* x      = (const float*)d_in[0];
  const float* w_qkv  = (const float*)d_in[1];
  const float* w_proj = (const float*)d_in[2];
  const float* b_proj = (const float*)d_in[3];
  float* out = (float*)d_out;
  f16* ws = (f16*)d_ws;

  const size_t W16T = 4608ull * 768;
  const size_t WPT  = 768ull * 768;
  f16* w16t = ws;
  f16* wpt  = ws + W16T;
  f16* area = wpt + WPT;

  int G = 8;  // batches per chunk; shrink until scratch fits
  while (G > 1 && (W16T + WPT + 8ull * G * S3) * 2 > ws_size) G >>= 1;
  int nch = 8 / G;
  long long cstr = (long long)G * S3;
  f16* x16 = area + 7 * (size_t)cstr;   // aliases comp7 (prod) - dead until attn_chan

  cvt_T_kernel<<<dim3(144, 24), 256, 0, stream>>>(w_qkv, w16t, 768, 4608);
  cvt_T_kernel<<<dim3(24, 24), 256, 0, stream>>>(w_proj, wpt, 768, 768);

  for (int ch = 0; ch < nch; ch++) {
    size_t b0 = (size_t)ch * G;
    cvt_x_kernel<<<G * 1536, 256, 0, stream>>>(x + b0 * S3, x16);
    gemm_qkv8<<<G * 288, 512, 0, stream>>>(x16, w16t, area, cstr);
    attn_spat_kernel<<<G * 192, 512, 0, stream>>>(area, cstr);
    attn_chan_kernel<<<G * 256, 256, 0, stream>>>(area, cstr);
    gemm_proj8<<<G * 48, 512, 0, stream>>>(area + 7 * (size_t)cstr, wpt, b_proj,
                                           out + b0 * S3);
  }
}

// Round 11
// 573.022 us; speedup vs baseline: 1.0333x; 1.0333x over previous
//
#include <hip/hip_runtime.h>

typedef _Float16 f16;
typedef f16  f16x8 __attribute__((ext_vector_type(8)));
typedef float f32x4 __attribute__((ext_vector_type(4)));

#define S3 3145728LL   // per-batch per-component elems (12*256*16*64 = 4096*768)

__device__ __forceinline__ f32x4 mm(f16x8 a, f16x8 b, f32x4 c) {
  return __builtin_amdgcn_mfma_f32_16x16x32_f16(a, b, c, 0, 0, 0);
}
__device__ __forceinline__ void BAR() { asm volatile("s_barrier" ::: "memory"); }

// epilogue LDS swizzle for [128][128] f16 tile
__device__ __forceinline__ int esw(int t, int col) {
  return t * 128 + ((((col >> 3) ^ ((t ^ (t >> 3)) & 7)) << 3) | (col & 7));
}
// epilogue LDS swizzle for [256][256] tile (kept for reference/unused)

// ---------------- transpose + fp32->fp16 convert: out[Cc][R] = in[R][Cc] ----
__global__ void cvt_T_kernel(const float* __restrict__ in, f16* __restrict__ out,
                             int R, int Cc) {
  __shared__ float tile[32][33];
  int tc = blockIdx.x, tr = blockIdx.y;
  int lr = threadIdx.x & 31, lw = threadIdx.x >> 5;
  int c0 = tc * 32, r0 = tr * 32;
#pragma unroll
  for (int i = 0; i < 4; i++)
    tile[lw + 8 * i][lr] = in[(size_t)(r0 + lw + 8 * i) * Cc + c0 + lr];
  __syncthreads();
#pragma unroll
  for (int i = 0; i < 4; i++)
    out[(size_t)(c0 + lw + 8 * i) * R + r0 + lr] = (f16)tile[lr][lw + 8 * i];
}

// ---------------- x fp32 -> f16 (NT reads: x is never re-read) -------------
__global__ void cvt_x_kernel(const float* __restrict__ in, f16* __restrict__ out) {
  size_t i = ((size_t)blockIdx.x * 256 + threadIdx.x) * 8;
  f32x4 a = __builtin_nontemporal_load((const f32x4*)(in + i));
  f32x4 b = __builtin_nontemporal_load((const f32x4*)(in + i + 4));
  f16x8 o;
#pragma unroll
  for (int j = 0; j < 4; j++) { o[j] = (f16)a[j]; o[4 + j] = (f16)b[j]; }
  *(f16x8*)(out + i) = o;
}

// =================== QKV GEMM: 128x128 tile, BK=64, 64KB LDS ================
// 256 threads (4 waves, 2x2), 2 blocks/CU. Ahead-1 pipeline per K-tile:
//   ds_read frags -> lgkmcnt(0) -> BAR -> stage(t+2 into this buf) ->
//   32 MFMA -> vmcnt(8) [tail: 0] -> BAR
// Per-wave vmcnt(8): each wave's own t+2 batch is the only thing outstanding,
// so at the barrier every wave's t+1 rows have landed.
#define QST_A(c, q, kt) __builtin_amdgcn_global_load_lds( \
    (const __attribute__((address_space(1))) void*)(aSrc + (size_t)(q) * 24576 + (size_t)(kt) * 64), \
    (__attribute__((address_space(3))) void*)((char*)lds + (c) * 32768 + (q) * 1024 * 4 + wave * 1024), 16, 0, 0)
#define QST_B(c, q, kt) __builtin_amdgcn_global_load_lds( \
    (const __attribute__((address_space(1))) void*)(bSrc + (size_t)(q) * 24576 + (size_t)(kt) * 64), \
    (__attribute__((address_space(3))) void*)((char*)lds + 16384 + (c) * 32768 + (q) * 1024 * 4 + wave * 1024), 16, 0, 0)

__global__ __launch_bounds__(256, 2) void gemm_qkvT(
    const f16* __restrict__ A, const f16* __restrict__ Bt,
    f16* __restrict__ area, long long cstr_) {
  __shared__ f16 lds[32768];   // 64KB: 2 x (A 16KB | B 16KB); epilogue reuses 32KB
  size_t cstr = (size_t)cstr_;
  int id  = blockIdx.x;
  int cpx = gridDim.x >> 3;
  int id2 = (id & 7) * cpx + (id >> 3);       // XCD swizzle (grid % 8 == 0)
  int sr = id2 / 288, rr = id2 % 288;
  int bm = sr * 8 + (rr & 7), bn = rr >> 3;   // bm 0..G*32-1, bn 0..35

  int tid = threadIdx.x;
  int wave = tid >> 6, lane = tid & 63;
  int l16 = lane & 15, lq = lane >> 4;
  int wr = wave >> 1, wc = wave & 1;          // 2 x 2 wave grid
  int l7 = l16 & 7;
  int cb0 = ((lq) ^ l7) << 4;                 // granule ks=0
  int cb1 = ((4 + lq) ^ l7) << 4;             // granule ks=1

  // pre-swizzled global sources (linear LDS dest; col granule ^= row&7)
  const f16* aSrc = A  + (size_t)(bm * 128 + (tid >> 3)) * 768 +
                    (((tid & 7) ^ ((tid >> 3) & 7)) << 3);
  const f16* bSrc = Bt + (size_t)(bn * 128 + (tid >> 3)) * 768 +
                    (((tid & 7) ^ ((tid >> 3) & 7)) << 3);

  f32x4 zz = {0.f, 0.f, 0.f, 0.f};
  f32x4 acc[4][4];
#pragma unroll
  for (int m = 0; m < 4; m++)
#pragma unroll
    for (int n = 0; n < 4; n++) acc[m][n] = zz;

  // prologue: tile0 + tile1 fully (8 loads each per wave)
#pragma unroll
  for (int q = 0; q < 4; q++) { QST_A(0, q, 0); }
#pragma unroll
  for (int q = 0; q < 4; q++) { QST_B(0, q, 0); }
#pragma unroll
  for (int q = 0; q < 4; q++) { QST_A(1, q, 1); }
#pragma unroll
  for (int q = 0; q < 4; q++) { QST_B(1, q, 1); }
  asm volatile("s_waitcnt vmcnt(8)" ::: "memory");
  BAR();

  f16x8 af[4][2], bf[4][2];
#pragma unroll 2
  for (int t = 0; t < 12; ++t) {
    int c = t & 1;
    const char* ab = (const char*)lds + c * 32768;
    const char* bb = ab + 16384;
    int rA = wr * 64 + l16;
    int rB = wc * 64 + l16;
#pragma unroll
    for (int mf = 0; mf < 4; mf++) {
      af[mf][0] = *(const f16x8*)(ab + (rA + mf * 16) * 128 + cb0);
      af[mf][1] = *(const f16x8*)(ab + (rA + mf * 16) * 128 + cb1);
    }
#pragma unroll
    for (int nf = 0; nf < 4; nf++) {
      bf[nf][0] = *(const f16x8*)(bb + (rB + nf * 16) * 128 + cb0);
      bf[nf][1] = *(const f16x8*)(bb + (rB + nf * 16) * 128 + cb1);
    }
    // all reads of this buffer done (per-wave), then block-wide rendezvous
    asm volatile("s_waitcnt lgkmcnt(0)" ::: "memory");
    BAR();
    if (t < 10) {   // overwrite this buffer with tile t+2
#pragma unroll
      for (int q = 0; q < 4; q++) { QST_A(c, q, t + 2); }
#pragma unroll
      for (int q = 0; q < 4; q++) { QST_B(c, q, t + 2); }
    }
    __builtin_amdgcn_s_setprio(1);
#pragma unroll
    for (int ks = 0; ks < 2; ks++)
#pragma unroll
      for (int mf = 0; mf < 4; mf++)
#pragma unroll
        for (int nf = 0; nf < 4; nf++)
          acc[mf][nf] = mm(af[mf][ks], bf[nf][ks], acc[mf][nf]);
    __builtin_amdgcn_s_setprio(0);
    if (t < 10) asm volatile("s_waitcnt vmcnt(8)" ::: "memory");
    else        asm volatile("s_waitcnt vmcnt(0)" ::: "memory");
    BAR();
  }

  // ---- coalesced LDS epilogue (32KB [128][128] C-tile) ----
  // bn-tile lies in ONE component s = bn/6; covers heads h0..h0+1, n0..n0+7.
  //  qc/kc [h][n][c][d]; qs/ks [h][c][n][d]; vc [h][n][d][c];
  //  vs BLOCKED [h][c][nb8 32][d 64][nl8 8]  (nb8 = n>>3 = bm&31).
  int s  = bn / 6;
  int h0 = (bn % 6) * 2;
  size_t comp;
  if (s == 0) comp = 0; else if (s == 1) comp = 1; else if (s == 2) comp = 3;
  else if (s == 3) comp = 4; else if (s == 4) comp = 2; else comp = 5;
  int g = (bm * 128) >> 12;
  size_t base = comp * cstr + (size_t)g * S3;
  int n0 = (bm & 31) * 8;

  __syncthreads();
#pragma unroll
  for (int mi = 0; mi < 4; mi++)
#pragma unroll
    for (int ni = 0; ni < 4; ni++)
#pragma unroll
      for (int r = 0; r < 4; r++) {
        int t = wr * 64 + mi * 16 + lq * 4 + r;
        int col = wc * 64 + ni * 16 + l16;
        lds[esw(t, col)] = (f16)acc[mi][ni][r];
      }
  __syncthreads();

  if (s < 2) {            // qc/kc: 16 units of 2KB (hl x n-group)
#pragma unroll
    for (int i = 0; i < 4; i++) {
      int u = wave * 4 + i;
      int hl = u >> 3, j16 = u & 7;
#pragma unroll
      for (int half = 0; half < 2; half++) {
        int e0 = half * 512 + lane * 8;
        int cc = e0 >> 6, d0 = e0 & 63;
        f16x8 v = *(const f16x8*)&lds[esw(j16 * 16 + cc, hl * 64 + d0)];
        __builtin_nontemporal_store(v, (f16x8*)&area[base +
            (size_t)(h0 + hl) * 262144 + (size_t)(n0 + j16) * 1024 + e0]);
      }
    }
  } else if (s < 4) {     // qs/ks: 32 units of 1KB (hl x c)
#pragma unroll
    for (int i = 0; i < 8; i++) {
      int u = wave * 8 + i;
      int hl = u >> 4, cc = u & 15;
      int e = lane * 8;
      int nl = e >> 6, d0 = e & 63;
      f16x8 v = *(const f16x8*)&lds[esw(nl * 16 + cc, hl * 64 + d0)];
      __builtin_nontemporal_store(v, (f16x8*)&area[base +
          (size_t)((h0 + hl) * 16 + cc) * 16384 + (size_t)n0 * 64 + e]);
    }
  } else if (s == 4) {    // vc: 16 units of 2KB (hl x n)
#pragma unroll
    for (int i = 0; i < 4; i++) {
      int u = wave * 4 + i;
      int hl = u >> 3, j8 = u & 7;
#pragma unroll
      for (int half = 0; half < 2; half++) {
        int e0 = half * 512 + lane * 8;
        int d0 = e0 >> 4, cb = e0 & 15;
        f16x8 v;
#pragma unroll
        for (int j = 0; j < 8; j++)
          v[j] = lds[esw(j8 * 16 + cb + j, hl * 64 + d0)];
        __builtin_nontemporal_store(v, (f16x8*)&area[base +
            (size_t)((h0 + hl) * 256 + n0 + j8) * 1024 + e0]);
      }
    }
  } else {                // vs blocked: 32 units of 1KB (hl x c); e = d*8+nl
#pragma unroll
    for (int i = 0; i < 8; i++) {
      int u = wave * 8 + i;
      int hl = u >> 4, cc = u & 15;
      int e = lane * 8;
      int d0 = e >> 3;
      f16x8 v;
#pragma unroll
      for (int j = 0; j < 8; j++)
        v[j] = lds[esw(j * 16 + cc, hl * 64 + d0)];
      __builtin_nontemporal_store(v, (f16x8*)&area[base +
          ((size_t)((h0 + hl) * 16 + cc) * 32 + (bm & 31)) * 512 + e]);
    }
  }
}

// ---------------- proj GEMM: 256x256 tile, 2-phase (unchanged from R10) -----
#define STG_A(c, q, kt) __builtin_amdgcn_global_load_lds( \
    (const __attribute__((address_space(1))) void*)(aSrc + (size_t)(q) * 49152 + (size_t)(kt) * 64), \
    (__attribute__((address_space(3))) void*)(lds + (c) * 32768 + (q) * 4096 + wave * 512), 16, 0, 0)
#define STG_B(c, q, kt) __builtin_amdgcn_global_load_lds( \
    (const __attribute__((address_space(1))) void*)(bSrc + (size_t)(q) * 49152 + (size_t)(kt) * 64), \
    (__attribute__((address_space(3))) void*)(lds + 16384 + (c) * 32768 + (q) * 4096 + wave * 512), 16, 0, 0)

__global__ __launch_bounds__(512, 2) void gemm_proj8(
    const f16* __restrict__ A, const f16* __restrict__ Bt,
    const float* __restrict__ bias, float* __restrict__ Cout) {
  __shared__ f16 lds[65536];
  int id  = blockIdx.x;
  int cpx = gridDim.x >> 3;
  int id2 = (id & 7) * cpx + (id >> 3);
  int sr = id2 / 24, rr = id2 % 24;
  int bm = sr * 8 + (rr & 7), bn = rr >> 3;

  int tid = threadIdx.x;
  int wave = tid >> 6, lane = tid & 63;
  int l16 = lane & 15, lq = lane >> 4;
  int wr = wave >> 2, wc = wave & 3;
  int sx  = (l16 & 7) << 4;
  int cb0 = (lq * 16) ^ sx;
  int cb1 = (64 + lq * 16) ^ sx;

  int scol = ((tid & 7) ^ ((tid >> 3) & 7)) << 3;
  const f16* aSrc = A  + (size_t)(bm * 256 + (tid >> 3)) * 768 + scol;
  const f16* bSrc = Bt + (size_t)(bn * 256 + (tid >> 3)) * 768 + scol;

  f32x4 zz = {0.f, 0.f, 0.f, 0.f};
  f32x4 acc[8][4];
#pragma unroll
  for (int m = 0; m < 8; m++)
#pragma unroll
    for (int n = 0; n < 4; n++) acc[m][n] = zz;

  STG_A(0, 0, 0); STG_A(0, 1, 0); STG_A(0, 2, 0); STG_A(0, 3, 0);
  STG_B(0, 0, 0); STG_B(0, 1, 0); STG_B(0, 2, 0); STG_B(0, 3, 0);
  STG_A(1, 1, 1); STG_A(1, 3, 1);
  STG_B(1, 0, 1); STG_B(1, 1, 1);
  asm volatile("s_waitcnt vmcnt(4)" ::: "memory");
  BAR();

  f16x8 af[4][2], ag[4][2], bf[2][2], bg[2][2];
#pragma unroll 2
  for (int t = 0; t < 12; ++t) {
    int c = t & 1, nb = c ^ 1;
    const char* ab = (const char*)lds + c * 65536;
    const char* bb = ab + 32768;
    int rA = wr * 128 + l16;
    int rB = wc * 64 + l16;
#pragma unroll
    for (int mf = 0; mf < 4; mf++) {
      af[mf][0] = *(const f16x8*)(ab + (rA + mf * 16) * 128 + cb0);
      af[mf][1] = *(const f16x8*)(ab + (rA + mf * 16) * 128 + cb1);
    }
#pragma unroll
    for (int nf = 0; nf < 2; nf++) {
      bf[nf][0] = *(const f16x8*)(bb + (rB + nf * 16) * 128 + cb0);
      bf[nf][1] = *(const f16x8*)(bb + (rB + nf * 16) * 128 + cb1);
      bg[nf][0] = *(const f16x8*)(bb + (rB + 32 + nf * 16) * 128 + cb0);
      bg[nf][1] = *(const f16x8*)(bb + (rB + 32 + nf * 16) * 128 + cb1);
    }
    if (t < 11) {
      STG_B(nb, 2, t + 1); STG_B(nb, 3, t + 1);
      STG_A(nb, 0, t + 1); STG_A(nb, 2, t + 1);
    }
    BAR();
    __builtin_amdgcn_s_setprio(1);
#pragma unroll
    for (int ks = 0; ks < 2; ks++)
#pragma unroll
      for (int mf = 0; mf < 4; mf++)
#pragma unroll
        for (int nf = 0; nf < 2; nf++) {
          acc[mf][nf]     = mm(af[mf][ks], bf[nf][ks], acc[mf][nf]);
          acc[mf][2 + nf] = mm(af[mf][ks], bg[nf][ks], acc[mf][2 + nf]);
        }
    __builtin_amdgcn_s_setprio(0);
    BAR();
#pragma unroll
    for (int mf = 0; mf < 4; mf++) {
      ag[mf][0] = *(const f16x8*)(ab + (rA + 64 + mf * 16) * 128 + cb0);
      ag[mf][1] = *(const f16x8*)(ab + (rA + 64 + mf * 16) * 128 + cb1);
    }
    if (t < 10) {
      STG_A(c, 1, t + 2); STG_A(c, 3, t + 2);
      STG_B(c, 0, t + 2); STG_B(c, 1, t + 2);
    }
    BAR();
    __builtin_amdgcn_s_setprio(1);
#pragma unroll
    for (int ks = 0; ks < 2; ks++)
#pragma unroll
      for (int mf = 0; mf < 4; mf++)
#pragma unroll
        for (int nf = 0; nf < 2; nf++) {
          acc[4 + mf][nf]     = mm(ag[mf][ks], bf[nf][ks], acc[4 + mf][nf]);
          acc[4 + mf][2 + nf] = mm(ag[mf][ks], bg[nf][ks], acc[4 + mf][2 + nf]);
        }
    __builtin_amdgcn_s_setprio(0);
    if (t < 10) asm volatile("s_waitcnt vmcnt(4)" ::: "memory");
    else        asm volatile("s_waitcnt vmcnt(0)" ::: "memory");
    BAR();
  }

#pragma unroll
  for (int ni = 0; ni < 4; ni++) {
    int col = bn * 256 + wc * 64 + ni * 16 + l16;
    float bb = bias[col];
#pragma unroll
    for (int mi = 0; mi < 8; mi++) {
#pragma unroll
      for (int r = 0; r < 4; r++) {
        int row = bm * 256 + wr * 128 + (mi >> 2) * 64 + (mi & 3) * 16 + lq * 4 + r;
        __builtin_nontemporal_store(acc[mi][ni][r] + bb,
                                    &Cout[(size_t)row * 768 + col]);
      }
    }
  }
}

// ---------------- spatial attention: per (g,h,c), flash over N=256 ----------
__global__ __launch_bounds__(512) void attn_spat_kernel(f16* __restrict__ area,
                                                        long long cstr_) {
  size_t cstr = (size_t)cstr_;
  int blk = blockIdx.x;
  int g = blk / 192, rem = blk % 192;
  int h = rem >> 4, c = rem & 15;
  size_t goff = (size_t)g * S3;
  const f16* qs = area + 3 * cstr + goff + (size_t)((h * 16 + c) * 256) * 64;
  const f16* ks = area + 4 * cstr + goff + (size_t)((h * 16 + c) * 256) * 64;
  const f16* vsb = area + 5 * cstr + goff + (size_t)(h * 16 + c) * 16384; // [nb8][d][nl8]
  f16* xs = area + 6 * cstr + goff + (size_t)((h * 16 + c) * 256) * 64;

  int wave = threadIdx.x >> 6, lane = threadIdx.x & 63;
  int l16 = lane & 15, lq = lane >> 4;
  __shared__ f16 plds[8][32][40];

  f32x4 zz = {0.f, 0.f, 0.f, 0.f};
  f16x8 aq[2][2];
#pragma unroll
  for (int m = 0; m < 2; m++)
#pragma unroll
    for (int kd = 0; kd < 2; kd++)
      aq[m][kd] = *(const f16x8*)&qs[(size_t)(wave * 32 + m * 16 + l16) * 64 + kd * 32 + lq * 8];

  f32x4 o[2][4];
  float mrow[2][4], lrow[2][4];
#pragma unroll
  for (int m = 0; m < 2; m++) {
#pragma unroll
    for (int n = 0; n < 4; n++) o[m][n] = zz;
#pragma unroll
    for (int r = 0; r < 4; r++) { mrow[m][r] = -1e30f; lrow[m][r] = 0.f; }
  }

  for (int kc = 0; kc < 8; kc++) {
    int k0 = kc * 32;
    f16x8 bk00 = *(const f16x8*)&ks[(size_t)(k0 + l16) * 64 + lq * 8];
    f16x8 bk01 = *(const f16x8*)&ks[(size_t)(k0 + l16) * 64 + 32 + lq * 8];
    f16x8 bk10 = *(const f16x8*)&ks[(size_t)(k0 + 16 + l16) * 64 + lq * 8];
    f16x8 bk11 = *(const f16x8*)&ks[(size_t)(k0 + 16 + l16) * 64 + 32 + lq * 8];
    f32x4 st[2][2];
#pragma unroll
    for (int m = 0; m < 2; m++) {
      st[m][0] = mm(aq[m][1], bk01, mm(aq[m][0], bk00, zz));
      st[m][1] = mm(aq[m][1], bk11, mm(aq[m][0], bk10, zz));
    }
#pragma unroll
    for (int m = 0; m < 2; m++) {
#pragma unroll
      for (int r = 0; r < 4; r++) {
        float s0 = st[m][0][r] * 0.125f, s1 = st[m][1][r] * 0.125f;
        float t = fmaxf(s0, s1);
        t = fmaxf(t, __shfl_xor(t, 1));
        t = fmaxf(t, __shfl_xor(t, 2));
        t = fmaxf(t, __shfl_xor(t, 4));
        t = fmaxf(t, __shfl_xor(t, 8));
        float mold = mrow[m][r];
        float mnew = fmaxf(mold, t);
        float fac  = __expf(mold - mnew);
        mrow[m][r] = mnew;
        float p0 = __expf(s0 - mnew), p1 = __expf(s1 - mnew);
        lrow[m][r] = lrow[m][r] * fac + p0 + p1;
        o[m][0][r] *= fac; o[m][1][r] *= fac; o[m][2][r] *= fac; o[m][3][r] *= fac;
        int prow = m * 16 + lq * 4 + r;
        plds[wave][prow][l16]      = (f16)p0;
        plds[wave][prow][16 + l16] = (f16)p1;
      }
    }
    f16x8 ap0 = *(const f16x8*)&plds[wave][l16][lq * 8];
    f16x8 ap1 = *(const f16x8*)&plds[wave][16 + l16][lq * 8];
#pragma unroll
    for (int n = 0; n < 4; n++) {
      f16x8 bv = *(const f16x8*)&vsb[((k0 >> 3) + lq) * 512 + (n * 16 + l16) * 8];
      o[0][n] = mm(ap0, bv, o[0][n]);
      o[1][n] = mm(ap1, bv, o[1][n]);
    }
  }
#pragma unroll
  for (int m = 0; m < 2; m++)
#pragma unroll
    for (int r = 0; r < 4; r++) {
      float l = lrow[m][r];
      l += __shfl_xor(l, 1);
      l += __shfl_xor(l, 2);
      l += __shfl_xor(l, 4);
      l += __shfl_xor(l, 8);
      lrow[m][r] = 1.0f / l;
    }
#pragma unroll
  for (int m = 0; m < 2; m++)
#pragma unroll
    for (int n = 0; n < 4; n++)
#pragma unroll
      for (int r = 0; r < 4; r++) {
        int row = wave * 32 + m * 16 + lq * 4 + r;
        xs[(size_t)row * 64 + n * 16 + l16] = (f16)(o[m][n][r] * lrow[m][r]);
      }
}

// ---------------- channel attention + combine: per (g,n), 12 heads ----------
__global__ __launch_bounds__(256) void attn_chan_kernel(f16* __restrict__ area,
                                                        long long cstr_) {
  size_t cstr = (size_t)cstr_;
  int blk = blockIdx.x;
  int g = blk >> 8, n = blk & 255;
  size_t goff = (size_t)g * S3;
  int wave = threadIdx.x >> 6, lane = threadIdx.x & 63;
  int l16 = lane & 15, lq = lane >> 4;
  __shared__ f16 plds[4][16][40];
  if (lane < 16) {
#pragma unroll
    for (int j = 0; j < 16; j++) plds[wave][lane][16 + j] = (f16)0.f;
  }
  const f16* xs = area + 6 * cstr + goff;
  f16* prod = area + 7 * cstr + goff;
  f32x4 zz = {0.f, 0.f, 0.f, 0.f};
  for (int hi = 0; hi < 3; hi++) {
    int h = wave + hi * 4;
    const f16* q = area + 0 * cstr + goff + (size_t)((h * 256 + n) * 16) * 64;
    const f16* k = area + 1 * cstr + goff + (size_t)((h * 256 + n) * 16) * 64;
    const f16* v = area + 2 * cstr + goff + (size_t)((h * 256 + n) * 64) * 16;
    f16x8 a0 = *(const f16x8*)&q[l16 * 64 + lq * 8];
    f16x8 a1 = *(const f16x8*)&q[l16 * 64 + 32 + lq * 8];
    f16x8 b0 = *(const f16x8*)&k[l16 * 64 + lq * 8];
    f16x8 b1 = *(const f16x8*)&k[l16 * 64 + 32 + lq * 8];
    f32x4 s = mm(a1, b1, mm(a0, b0, zz));
    float p[4];
#pragma unroll
    for (int r = 0; r < 4; r++) {
      float t = s[r] * 0.125f;
      float mx = t;
      mx = fmaxf(mx, __shfl_xor(mx, 1));
      mx = fmaxf(mx, __shfl_xor(mx, 2));
      mx = fmaxf(mx, __shfl_xor(mx, 4));
      mx = fmaxf(mx, __shfl_xor(mx, 8));
      float e = __expf(t - mx);
      float sum = e;
      sum += __shfl_xor(sum, 1);
      sum += __shfl_xor(sum, 2);
      sum += __shfl_xor(sum, 4);
      sum += __shfl_xor(sum, 8);
      p[r] = e / sum;
    }
#pragma unroll
    for (int r = 0; r < 4; r++)
      plds[wave][lq * 4 + r][l16] = (f16)p[r];
    f16x8 ap = *(const f16x8*)&plds[wave][l16][lq * 8];
#pragma unroll
    for (int nt = 0; nt < 4; nt++) {
      f16x8 bv = *(const f16x8*)&v[(nt * 16 + l16) * 16 + lq * 8];
      f32x4 o = mm(ap, bv, zz);
#pragma unroll
      for (int r = 0; r < 4; r++) {
        int cq = lq * 4 + r, d = nt * 16 + l16;
        float xsv = (float)xs[(size_t)((h * 16 + cq) * 256 + n) * 64 + d];
        prod[(size_t)n * 12288 + h * 1024 + cq * 64 + d] = (f16)(o[r] * xsv);
      }
    }
  }
}

// ---------------- host ------------------------------------------------------
extern "C" void kernel_launch(void* const* d_in, const int* in_sizes, int n_in,
                              void* d_out, int out_size, void* d_ws, size_t ws_size,
                              hipStream_t stream) {
  const float* x      = (const float*)d_in[0];
  const float* w_qkv  = (const float*)d_in[1];
  const float* w_proj = (const float*)d_in[2];
  const float* b_proj = (const float*)d_in[3];
  float* out = (float*)d_out;
  f16* ws = (f16*)d_ws;

  const size_t W16T = 4608ull * 768;
  const size_t WPT  = 768ull * 768;
  f16* w16t = ws;
  f16* wpt  = ws + W16T;
  f16* area = wpt + WPT;

  int G = 8;  // batches per chunk; shrink until scratch fits
  while (G > 1 && (W16T + WPT + 8ull * G * S3) * 2 > ws_size) G >>= 1;
  int nch = 8 / G;
  long long cstr = (long long)G * S3;
  f16* x16 = area + 7 * (size_t)cstr;   // aliases comp7 (prod) - dead until attn_chan

  cvt_T_kernel<<<dim3(144, 24), 256, 0, stream>>>(w_qkv, w16t, 768, 4608);
  cvt_T_kernel<<<dim3(24, 24), 256, 0, stream>>>(w_proj, wpt, 768, 768);

  for (int ch = 0; ch < nch; ch++) {
    size_t b0 = (size_t)ch * G;
    cvt_x_kernel<<<G * 1536, 256, 0, stream>>>(x + b0 * S3, x16);
    gemm_qkvT<<<G * 1152, 256, 0, stream>>>(x16, w16t, area, cstr);
    attn_spat_kernel<<<G * 192, 512, 0, stream>>>(area, cstr);
    attn_chan_kernel<<<G * 256, 256, 0, stream>>>(area, cstr);
    gemm_proj8<<<G * 48, 512, 0, stream>>>(area + 7 * (size_t)cstr, wpt, b_proj,
                                           out + b0 * S3);
  }
}

// Round 12
// 544.090 us; speedup vs baseline: 1.0883x; 1.0532x over previous
//
#include <hip/hip_runtime.h>

typedef _Float16 f16;
typedef f16  f16x8 __attribute__((ext_vector_type(8)));
typedef float f32x4 __attribute__((ext_vector_type(4)));

#define S3 3145728LL   // per-batch per-component elems (12*256*16*64 = 4096*768)

__device__ __forceinline__ f32x4 mm(f16x8 a, f16x8 b, f32x4 c) {
  return __builtin_amdgcn_mfma_f32_16x16x32_f16(a, b, c, 0, 0, 0);
}
__device__ __forceinline__ void BAR() { asm volatile("s_barrier" ::: "memory"); }

// epilogue LDS swizzle for [128][128] f16 tile
__device__ __forceinline__ int esw(int t, int col) {
  return t * 128 + ((((col >> 3) ^ ((t ^ (t >> 3)) & 7)) << 3) | (col & 7));
}
// swizzle for [256][64] f16 tile (attn_spat O staging)
__device__ __forceinline__ int oesw(int t, int col) {
  return t * 64 + ((((col >> 3) ^ (t & 7)) << 3) | (col & 7));
}

// ---------------- transpose + fp32->fp16 convert: out[Cc][R] = in[R][Cc] ----
__global__ void cvt_T_kernel(const float* __restrict__ in, f16* __restrict__ out,
                             int R, int Cc) {
  __shared__ float tile[32][33];
  int tc = blockIdx.x, tr = blockIdx.y;
  int lr = threadIdx.x & 31, lw = threadIdx.x >> 5;
  int c0 = tc * 32, r0 = tr * 32;
#pragma unroll
  for (int i = 0; i < 4; i++)
    tile[lw + 8 * i][lr] = in[(size_t)(r0 + lw + 8 * i) * Cc + c0 + lr];
  __syncthreads();
#pragma unroll
  for (int i = 0; i < 4; i++)
    out[(size_t)(c0 + lw + 8 * i) * R + r0 + lr] = (f16)tile[lr][lw + 8 * i];
}

// ---------------- x fp32 -> f16 (NT reads: x is never re-read) -------------
__global__ void cvt_x_kernel(const float* __restrict__ in, f16* __restrict__ out) {
  size_t i = ((size_t)blockIdx.x * 256 + threadIdx.x) * 8;
  f32x4 a = __builtin_nontemporal_load((const f32x4*)(in + i));
  f32x4 b = __builtin_nontemporal_load((const f32x4*)(in + i + 4));
  f16x8 o;
#pragma unroll
  for (int j = 0; j < 4; j++) { o[j] = (f16)a[j]; o[4 + j] = (f16)b[j]; }
  *(f16x8*)(out + i) = o;
}

// =================== QKV GEMM: 128x128 tile, BK=64, 64KB LDS ================
#define QST_A(c, q, kt) __builtin_amdgcn_global_load_lds( \
    (const __attribute__((address_space(1))) void*)(aSrc + (size_t)(q) * 24576 + (size_t)(kt) * 64), \
    (__attribute__((address_space(3))) void*)((char*)lds + (c) * 32768 + (q) * 1024 * 4 + wave * 1024), 16, 0, 0)
#define QST_B(c, q, kt) __builtin_amdgcn_global_load_lds( \
    (const __attribute__((address_space(1))) void*)(bSrc + (size_t)(q) * 24576 + (size_t)(kt) * 64), \
    (__attribute__((address_space(3))) void*)((char*)lds + 16384 + (c) * 32768 + (q) * 1024 * 4 + wave * 1024), 16, 0, 0)

__global__ __launch_bounds__(256, 2) void gemm_qkvT(
    const f16* __restrict__ A, const f16* __restrict__ Bt,
    f16* __restrict__ area, long long cstr_) {
  __shared__ f16 lds[32768];   // 64KB: 2 x (A 16KB | B 16KB); epilogue reuses 32KB
  size_t cstr = (size_t)cstr_;
  int id  = blockIdx.x;
  int cpx = gridDim.x >> 3;
  int id2 = (id & 7) * cpx + (id >> 3);       // XCD swizzle (grid % 8 == 0)
  int sr = id2 / 288, rr = id2 % 288;
  int bm = sr * 8 + (rr & 7), bn = rr >> 3;   // bm 0..G*32-1, bn 0..35

  int tid = threadIdx.x;
  int wave = tid >> 6, lane = tid & 63;
  int l16 = lane & 15, lq = lane >> 4;
  int wr = wave >> 1, wc = wave & 1;          // 2 x 2 wave grid
  int l7 = l16 & 7;
  int cb0 = ((lq) ^ l7) << 4;                 // granule ks=0
  int cb1 = ((4 + lq) ^ l7) << 4;             // granule ks=1

  const f16* aSrc = A  + (size_t)(bm * 128 + (tid >> 3)) * 768 +
                    (((tid & 7) ^ ((tid >> 3) & 7)) << 3);
  const f16* bSrc = Bt + (size_t)(bn * 128 + (tid >> 3)) * 768 +
                    (((tid & 7) ^ ((tid >> 3) & 7)) << 3);

  f32x4 zz = {0.f, 0.f, 0.f, 0.f};
  f32x4 acc[4][4];
#pragma unroll
  for (int m = 0; m < 4; m++)
#pragma unroll
    for (int n = 0; n < 4; n++) acc[m][n] = zz;

#pragma unroll
  for (int q = 0; q < 4; q++) { QST_A(0, q, 0); }
#pragma unroll
  for (int q = 0; q < 4; q++) { QST_B(0, q, 0); }
#pragma unroll
  for (int q = 0; q < 4; q++) { QST_A(1, q, 1); }
#pragma unroll
  for (int q = 0; q < 4; q++) { QST_B(1, q, 1); }
  asm volatile("s_waitcnt vmcnt(8)" ::: "memory");
  BAR();

  f16x8 af[4][2], bf[4][2];
#pragma unroll 2
  for (int t = 0; t < 12; ++t) {
    int c = t & 1;
    const char* ab = (const char*)lds + c * 32768;
    const char* bb = ab + 16384;
    int rA = wr * 64 + l16;
    int rB = wc * 64 + l16;
#pragma unroll
    for (int mf = 0; mf < 4; mf++) {
      af[mf][0] = *(const f16x8*)(ab + (rA + mf * 16) * 128 + cb0);
      af[mf][1] = *(const f16x8*)(ab + (rA + mf * 16) * 128 + cb1);
    }
#pragma unroll
    for (int nf = 0; nf < 4; nf++) {
      bf[nf][0] = *(const f16x8*)(bb + (rB + nf * 16) * 128 + cb0);
      bf[nf][1] = *(const f16x8*)(bb + (rB + nf * 16) * 128 + cb1);
    }
    asm volatile("s_waitcnt lgkmcnt(0)" ::: "memory");
    BAR();
    if (t < 10) {
#pragma unroll
      for (int q = 0; q < 4; q++) { QST_A(c, q, t + 2); }
#pragma unroll
      for (int q = 0; q < 4; q++) { QST_B(c, q, t + 2); }
    }
    __builtin_amdgcn_s_setprio(1);
#pragma unroll
    for (int ks = 0; ks < 2; ks++)
#pragma unroll
      for (int mf = 0; mf < 4; mf++)
#pragma unroll
        for (int nf = 0; nf < 4; nf++)
          acc[mf][nf] = mm(af[mf][ks], bf[nf][ks], acc[mf][nf]);
    __builtin_amdgcn_s_setprio(0);
    if (t < 10) asm volatile("s_waitcnt vmcnt(8)" ::: "memory");
    else        asm volatile("s_waitcnt vmcnt(0)" ::: "memory");
    BAR();
  }

  // ---- coalesced LDS epilogue (32KB [128][128] C-tile) ----
  int s  = bn / 6;
  int h0 = (bn % 6) * 2;
  size_t comp;
  if (s == 0) comp = 0; else if (s == 1) comp = 1; else if (s == 2) comp = 3;
  else if (s == 3) comp = 4; else if (s == 4) comp = 2; else comp = 5;
  int g = (bm * 128) >> 12;
  size_t base = comp * cstr + (size_t)g * S3;
  int n0 = (bm & 31) * 8;

  __syncthreads();
#pragma unroll
  for (int mi = 0; mi < 4; mi++)
#pragma unroll
    for (int ni = 0; ni < 4; ni++)
#pragma unroll
      for (int r = 0; r < 4; r++) {
        int t = wr * 64 + mi * 16 + lq * 4 + r;
        int col = wc * 64 + ni * 16 + l16;
        lds[esw(t, col)] = (f16)acc[mi][ni][r];
      }
  __syncthreads();

  if (s < 2) {            // qc/kc [h][n][c][d]
#pragma unroll
    for (int i = 0; i < 4; i++) {
      int u = wave * 4 + i;
      int hl = u >> 3, j16 = u & 7;
#pragma unroll
      for (int half = 0; half < 2; half++) {
        int e0 = half * 512 + lane * 8;
        int cc = e0 >> 6, d0 = e0 & 63;
        f16x8 v = *(const f16x8*)&lds[esw(j16 * 16 + cc, hl * 64 + d0)];
        __builtin_nontemporal_store(v, (f16x8*)&area[base +
            (size_t)(h0 + hl) * 262144 + (size_t)(n0 + j16) * 1024 + e0]);
      }
    }
  } else if (s < 4) {     // qs/ks [h][c][n][d]
#pragma unroll
    for (int i = 0; i < 8; i++) {
      int u = wave * 8 + i;
      int hl = u >> 4, cc = u & 15;
      int e = lane * 8;
      int nl = e >> 6, d0 = e & 63;
      f16x8 v = *(const f16x8*)&lds[esw(nl * 16 + cc, hl * 64 + d0)];
      __builtin_nontemporal_store(v, (f16x8*)&area[base +
          (size_t)((h0 + hl) * 16 + cc) * 16384 + (size_t)n0 * 64 + e]);
    }
  } else if (s == 4) {    // vc [h][n][d][c]
#pragma unroll
    for (int i = 0; i < 4; i++) {
      int u = wave * 4 + i;
      int hl = u >> 3, j8 = u & 7;
#pragma unroll
      for (int half = 0; half < 2; half++) {
        int e0 = half * 512 + lane * 8;
        int d0 = e0 >> 4, cb = e0 & 15;
        f16x8 v;
#pragma unroll
        for (int j = 0; j < 8; j++)
          v[j] = lds[esw(j8 * 16 + cb + j, hl * 64 + d0)];
        __builtin_nontemporal_store(v, (f16x8*)&area[base +
            (size_t)((h0 + hl) * 256 + n0 + j8) * 1024 + e0]);
      }
    }
  } else {                // vs blocked [h][c][nb8][d][nl8]
#pragma unroll
    for (int i = 0; i < 8; i++) {
      int u = wave * 8 + i;
      int hl = u >> 4, cc = u & 15;
      int e = lane * 8;
      int d0 = e >> 3;
      f16x8 v;
#pragma unroll
      for (int j = 0; j < 8; j++)
        v[j] = lds[esw(j * 16 + cc, hl * 64 + d0)];
      __builtin_nontemporal_store(v, (f16x8*)&area[base +
          ((size_t)((h0 + hl) * 16 + cc) * 32 + (bm & 31)) * 512 + e]);
    }
  }
}

// ---------------- proj GEMM: 256x256 tile, 2-phase (unchanged) --------------
#define STG_A(c, q, kt) __builtin_amdgcn_global_load_lds( \
    (const __attribute__((address_space(1))) void*)(aSrc + (size_t)(q) * 49152 + (size_t)(kt) * 64), \
    (__attribute__((address_space(3))) void*)(lds + (c) * 32768 + (q) * 4096 + wave * 512), 16, 0, 0)
#define STG_B(c, q, kt) __builtin_amdgcn_global_load_lds( \
    (const __attribute__((address_space(1))) void*)(bSrc + (size_t)(q) * 49152 + (size_t)(kt) * 64), \
    (__attribute__((address_space(3))) void*)(lds + 16384 + (c) * 32768 + (q) * 4096 + wave * 512), 16, 0, 0)

__global__ __launch_bounds__(512, 2) void gemm_proj8(
    const f16* __restrict__ A, const f16* __restrict__ Bt,
    const float* __restrict__ bias, float* __restrict__ Cout) {
  __shared__ f16 lds[65536];
  int id  = blockIdx.x;
  int cpx = gridDim.x >> 3;
  int id2 = (id & 7) * cpx + (id >> 3);
  int sr = id2 / 24, rr = id2 % 24;
  int bm = sr * 8 + (rr & 7), bn = rr >> 3;

  int tid = threadIdx.x;
  int wave = tid >> 6, lane = tid & 63;
  int l16 = lane & 15, lq = lane >> 4;
  int wr = wave >> 2, wc = wave & 3;
  int sx  = (l16 & 7) << 4;
  int cb0 = (lq * 16) ^ sx;
  int cb1 = (64 + lq * 16) ^ sx;

  int scol = ((tid & 7) ^ ((tid >> 3) & 7)) << 3;
  const f16* aSrc = A  + (size_t)(bm * 256 + (tid >> 3)) * 768 + scol;
  const f16* bSrc = Bt + (size_t)(bn * 256 + (tid >> 3)) * 768 + scol;

  f32x4 zz = {0.f, 0.f, 0.f, 0.f};
  f32x4 acc[8][4];
#pragma unroll
  for (int m = 0; m < 8; m++)
#pragma unroll
    for (int n = 0; n < 4; n++) acc[m][n] = zz;

  STG_A(0, 0, 0); STG_A(0, 1, 0); STG_A(0, 2, 0); STG_A(0, 3, 0);
  STG_B(0, 0, 0); STG_B(0, 1, 0); STG_B(0, 2, 0); STG_B(0, 3, 0);
  STG_A(1, 1, 1); STG_A(1, 3, 1);
  STG_B(1, 0, 1); STG_B(1, 1, 1);
  asm volatile("s_waitcnt vmcnt(4)" ::: "memory");
  BAR();

  f16x8 af[4][2], ag[4][2], bf[2][2], bg[2][2];
#pragma unroll 2
  for (int t = 0; t < 12; ++t) {
    int c = t & 1, nb = c ^ 1;
    const char* ab = (const char*)lds + c * 65536;
    const char* bb = ab + 32768;
    int rA = wr * 128 + l16;
    int rB = wc * 64 + l16;
#pragma unroll
    for (int mf = 0; mf < 4; mf++) {
      af[mf][0] = *(const f16x8*)(ab + (rA + mf * 16) * 128 + cb0);
      af[mf][1] = *(const f16x8*)(ab + (rA + mf * 16) * 128 + cb1);
    }
#pragma unroll
    for (int nf = 0; nf < 2; nf++) {
      bf[nf][0] = *(const f16x8*)(bb + (rB + nf * 16) * 128 + cb0);
      bf[nf][1] = *(const f16x8*)(bb + (rB + nf * 16) * 128 + cb1);
      bg[nf][0] = *(const f16x8*)(bb + (rB + 32 + nf * 16) * 128 + cb0);
      bg[nf][1] = *(const f16x8*)(bb + (rB + 32 + nf * 16) * 128 + cb1);
    }
    if (t < 11) {
      STG_B(nb, 2, t + 1); STG_B(nb, 3, t + 1);
      STG_A(nb, 0, t + 1); STG_A(nb, 2, t + 1);
    }
    BAR();
    __builtin_amdgcn_s_setprio(1);
#pragma unroll
    for (int ks = 0; ks < 2; ks++)
#pragma unroll
      for (int mf = 0; mf < 4; mf++)
#pragma unroll
        for (int nf = 0; nf < 2; nf++) {
          acc[mf][nf]     = mm(af[mf][ks], bf[nf][ks], acc[mf][nf]);
          acc[mf][2 + nf] = mm(af[mf][ks], bg[nf][ks], acc[mf][2 + nf]);
        }
    __builtin_amdgcn_s_setprio(0);
    BAR();
#pragma unroll
    for (int mf = 0; mf < 4; mf++) {
      ag[mf][0] = *(const f16x8*)(ab + (rA + 64 + mf * 16) * 128 + cb0);
      ag[mf][1] = *(const f16x8*)(ab + (rA + 64 + mf * 16) * 128 + cb1);
    }
    if (t < 10) {
      STG_A(c, 1, t + 2); STG_A(c, 3, t + 2);
      STG_B(c, 0, t + 2); STG_B(c, 1, t + 2);
    }
    BAR();
    __builtin_amdgcn_s_setprio(1);
#pragma unroll
    for (int ks = 0; ks < 2; ks++)
#pragma unroll
      for (int mf = 0; mf < 4; mf++)
#pragma unroll
        for (int nf = 0; nf < 2; nf++) {
          acc[4 + mf][nf]     = mm(ag[mf][ks], bf[nf][ks], acc[4 + mf][nf]);
          acc[4 + mf][2 + nf] = mm(ag[mf][ks], bg[nf][ks], acc[4 + mf][2 + nf]);
        }
    __builtin_amdgcn_s_setprio(0);
    if (t < 10) asm volatile("s_waitcnt vmcnt(4)" ::: "memory");
    else        asm volatile("s_waitcnt vmcnt(0)" ::: "memory");
    BAR();
  }

#pragma unroll
  for (int ni = 0; ni < 4; ni++) {
    int col = bn * 256 + wc * 64 + ni * 16 + l16;
    float bb = bias[col];
#pragma unroll
    for (int mi = 0; mi < 8; mi++) {
#pragma unroll
      for (int r = 0; r < 4; r++) {
        int row = bm * 256 + wr * 128 + (mi >> 2) * 64 + (mi & 3) * 16 + lq * 4 + r;
        __builtin_nontemporal_store(acc[mi][ni][r] + bb,
                                    &Cout[(size_t)row * 768 + col]);
      }
    }
  }
}

// ---------------- spatial attention: per (g,h,c); xs OUT = [n][h][c][d] -----
__global__ __launch_bounds__(512) void attn_spat_kernel(f16* __restrict__ area,
                                                        long long cstr_) {
  size_t cstr = (size_t)cstr_;
  int blk = blockIdx.x;
  int g = blk / 192, rem = blk % 192;
  int h = rem >> 4, c = rem & 15;
  size_t goff = (size_t)g * S3;
  const f16* qs = area + 3 * cstr + goff + (size_t)((h * 16 + c) * 256) * 64;
  const f16* ks = area + 4 * cstr + goff + (size_t)((h * 16 + c) * 256) * 64;
  const f16* vsb = area + 5 * cstr + goff + (size_t)(h * 16 + c) * 16384; // [nb8][d][nl8]
  f16* xsn = area + 6 * cstr + goff;   // [n][h][c][d]

  int tid = threadIdx.x;
  int wave = tid >> 6, lane = tid & 63;
  int l16 = lane & 15, lq = lane >> 4;
  __shared__ f16 plds[8][32][40];
  __shared__ f16 osm[16384];          // [256][64] swizzled (oesw)

  f32x4 zz = {0.f, 0.f, 0.f, 0.f};
  f16x8 aq[2][2];
#pragma unroll
  for (int m = 0; m < 2; m++)
#pragma unroll
    for (int kd = 0; kd < 2; kd++)
      aq[m][kd] = *(const f16x8*)&qs[(size_t)(wave * 32 + m * 16 + l16) * 64 + kd * 32 + lq * 8];

  f32x4 o[2][4];
  float mrow[2][4], lrow[2][4];
#pragma unroll
  for (int m = 0; m < 2; m++) {
#pragma unroll
    for (int n = 0; n < 4; n++) o[m][n] = zz;
#pragma unroll
    for (int r = 0; r < 4; r++) { mrow[m][r] = -1e30f; lrow[m][r] = 0.f; }
  }

  for (int kc = 0; kc < 8; kc++) {
    int k0 = kc * 32;
    f16x8 bk00 = *(const f16x8*)&ks[(size_t)(k0 + l16) * 64 + lq * 8];
    f16x8 bk01 = *(const f16x8*)&ks[(size_t)(k0 + l16) * 64 + 32 + lq * 8];
    f16x8 bk10 = *(const f16x8*)&ks[(size_t)(k0 + 16 + l16) * 64 + lq * 8];
    f16x8 bk11 = *(const f16x8*)&ks[(size_t)(k0 + 16 + l16) * 64 + 32 + lq * 8];
    f32x4 st[2][2];
#pragma unroll
    for (int m = 0; m < 2; m++) {
      st[m][0] = mm(aq[m][1], bk01, mm(aq[m][0], bk00, zz));
      st[m][1] = mm(aq[m][1], bk11, mm(aq[m][0], bk10, zz));
    }
#pragma unroll
    for (int m = 0; m < 2; m++) {
#pragma unroll
      for (int r = 0; r < 4; r++) {
        float s0 = st[m][0][r] * 0.125f, s1 = st[m][1][r] * 0.125f;
        float t = fmaxf(s0, s1);
        t = fmaxf(t, __shfl_xor(t, 1));
        t = fmaxf(t, __shfl_xor(t, 2));
        t = fmaxf(t, __shfl_xor(t, 4));
        t = fmaxf(t, __shfl_xor(t, 8));
        float mold = mrow[m][r];
        float mnew = fmaxf(mold, t);
        float fac  = __expf(mold - mnew);
        mrow[m][r] = mnew;
        float p0 = __expf(s0 - mnew), p1 = __expf(s1 - mnew);
        lrow[m][r] = lrow[m][r] * fac + p0 + p1;
        o[m][0][r] *= fac; o[m][1][r] *= fac; o[m][2][r] *= fac; o[m][3][r] *= fac;
        int prow = m * 16 + lq * 4 + r;
        plds[wave][prow][l16]      = (f16)p0;
        plds[wave][prow][16 + l16] = (f16)p1;
      }
    }
    f16x8 ap0 = *(const f16x8*)&plds[wave][l16][lq * 8];
    f16x8 ap1 = *(const f16x8*)&plds[wave][16 + l16][lq * 8];
#pragma unroll
    for (int n = 0; n < 4; n++) {
      f16x8 bv = *(const f16x8*)&vsb[((k0 >> 3) + lq) * 512 + (n * 16 + l16) * 8];
      o[0][n] = mm(ap0, bv, o[0][n]);
      o[1][n] = mm(ap1, bv, o[1][n]);
    }
  }
#pragma unroll
  for (int m = 0; m < 2; m++)
#pragma unroll
    for (int r = 0; r < 4; r++) {
      float l = lrow[m][r];
      l += __shfl_xor(l, 1);
      l += __shfl_xor(l, 2);
      l += __shfl_xor(l, 4);
      l += __shfl_xor(l, 8);
      lrow[m][r] = 1.0f / l;
    }
  // stage O in LDS, then full-line (128B) stores to xs[n][h][c][d]
#pragma unroll
  for (int m = 0; m < 2; m++)
#pragma unroll
    for (int n = 0; n < 4; n++)
#pragma unroll
      for (int r = 0; r < 4; r++) {
        int row = wave * 32 + m * 16 + lq * 4 + r;
        osm[oesw(row, n * 16 + l16)] = (f16)(o[m][n][r] * lrow[m][r]);
      }
  __syncthreads();
  size_t hc64 = (size_t)(h * 16 + c) * 64;
#pragma unroll
  for (int i = 0; i < 4; i++) {
    int row = i * 64 + (tid >> 3);
    int dp  = (tid & 7) * 8;
    f16x8 v = *(const f16x8*)&osm[oesw(row, dp)];
    __builtin_nontemporal_store(v, (f16x8*)&xsn[(size_t)row * 12288 + hc64 + dp]);
  }
}

// ---------------- channel attention + combine: per (g,n), 12 heads ----------
// xs IN = [n][h][c][d] contiguous 24KB per n; prod OUT = [n][h][c][d].
__global__ __launch_bounds__(256) void attn_chan_kernel(f16* __restrict__ area,
                                                        long long cstr_) {
  size_t cstr = (size_t)cstr_;
  int blk = blockIdx.x;
  int g = blk >> 8, n = blk & 255;
  size_t goff = (size_t)g * S3;
  int tid = threadIdx.x;
  int wave = tid >> 6, lane = tid & 63;
  int l16 = lane & 15, lq = lane >> 4;
  __shared__ f16 xsl[12288];   // 24 KB
  __shared__ f16 prl[12288];   // 24 KB
  __shared__ f16 plds[4][16][40];

  const f16* xsn = area + 6 * cstr + goff + (size_t)n * 12288;
#pragma unroll
  for (int i = 0; i < 6; i++) {
    int seg = wave * 6 + i;
    __builtin_amdgcn_global_load_lds(
        (const __attribute__((address_space(1))) void*)(xsn + seg * 512 + lane * 8),
        (__attribute__((address_space(3))) void*)((char*)xsl + seg * 1024), 16, 0, 0);
  }
  if (lane < 16) {
#pragma unroll
    for (int j = 0; j < 16; j++) plds[wave][lane][16 + j] = (f16)0.f;  // zero K-pad
  }
  asm volatile("s_waitcnt vmcnt(0)" ::: "memory");
  __syncthreads();

  f32x4 zz = {0.f, 0.f, 0.f, 0.f};
  for (int hi = 0; hi < 3; hi++) {
    int h = wave + hi * 4;
    const f16* q = area + 0 * cstr + goff + (size_t)((h * 256 + n) * 16) * 64;
    const f16* k = area + 1 * cstr + goff + (size_t)((h * 256 + n) * 16) * 64;
    const f16* v = area + 2 * cstr + goff + (size_t)((h * 256 + n) * 64) * 16; // [d][c]
    f16x8 a0 = *(const f16x8*)&q[l16 * 64 + lq * 8];
    f16x8 a1 = *(const f16x8*)&q[l16 * 64 + 32 + lq * 8];
    f16x8 b0 = *(const f16x8*)&k[l16 * 64 + lq * 8];
    f16x8 b1 = *(const f16x8*)&k[l16 * 64 + 32 + lq * 8];
    f32x4 s = mm(a1, b1, mm(a0, b0, zz));
    float p[4];
#pragma unroll
    for (int r = 0; r < 4; r++) {
      float t = s[r] * 0.125f;
      float mx = t;
      mx = fmaxf(mx, __shfl_xor(mx, 1));
      mx = fmaxf(mx, __shfl_xor(mx, 2));
      mx = fmaxf(mx, __shfl_xor(mx, 4));
      mx = fmaxf(mx, __shfl_xor(mx, 8));
      float e = __expf(t - mx);
      float sum = e;
      sum += __shfl_xor(sum, 1);
      sum += __shfl_xor(sum, 2);
      sum += __shfl_xor(sum, 4);
      sum += __shfl_xor(sum, 8);
      p[r] = e / sum;
    }
#pragma unroll
    for (int r = 0; r < 4; r++)
      plds[wave][lq * 4 + r][l16] = (f16)p[r];
    f16x8 ap = *(const f16x8*)&plds[wave][l16][lq * 8]; // k>=16 are zeros
#pragma unroll
    for (int nt = 0; nt < 4; nt++) {
      f16x8 bv = *(const f16x8*)&v[(nt * 16 + l16) * 16 + lq * 8];
      f32x4 o = mm(ap, bv, zz);
#pragma unroll
      for (int r = 0; r < 4; r++) {
        int cq = lq * 4 + r, d = nt * 16 + l16;
        int idx = h * 1024 + cq * 64 + d;
        float xsv = (float)xsl[idx];
        prl[idx] = (f16)(o[r] * xsv);
      }
    }
  }
  __syncthreads();
  f16* prod = area + 7 * cstr + goff + (size_t)n * 12288;
#pragma unroll
  for (int i = 0; i < 6; i++) {
    f16x8 v = *(const f16x8*)&prl[i * 2048 + tid * 8];
    __builtin_nontemporal_store(v, (f16x8*)&prod[i * 2048 + tid * 8]);
  }
}

// ---------------- host ------------------------------------------------------
extern "C" void kernel_launch(void* const* d_in, const int* in_sizes, int n_in,
                              void* d_out, int out_size, void* d_ws, size_t ws_size,
                              hipStream_t stream) {
  const float* x      = (const float*)d_in[0];
  const float* w_qkv  = (const float*)d_in[1];
  const float* w_proj = (const float*)d_in[2];
  const float* b_proj = (const float*)d_in[3];
  float* out = (float*)d_out;
  f16* ws = (f16*)d_ws;

  const size_t W16T = 4608ull * 768;
  const size_t WPT  = 768ull * 768;
  f16* w16t = ws;
  f16* wpt  = ws + W16T;
  f16* area = wpt + WPT;

  int G = 8;  // batches per chunk; shrink until scratch fits
  while (G > 1 && (W16T + WPT + 8ull * G * S3) * 2 > ws_size) G >>= 1;
  int nch = 8 / G;
  long long cstr = (long long)G * S3;
  f16* x16 = area + 7 * (size_t)cstr;   // aliases comp7 (prod) - dead until attn_chan

  cvt_T_kernel<<<dim3(144, 24), 256, 0, stream>>>(w_qkv, w16t, 768, 4608);
  cvt_T_kernel<<<dim3(24, 24), 256, 0, stream>>>(w_proj, wpt, 768, 768);

  for (int ch = 0; ch < nch; ch++) {
    size_t b0 = (size_t)ch * G;
    cvt_x_kernel<<<G * 1536, 256, 0, stream>>>(x + b0 * S3, x16);
    gemm_qkvT<<<G * 1152, 256, 0, stream>>>(x16, w16t, area, cstr);
    attn_spat_kernel<<<G * 192, 512, 0, stream>>>(area, cstr);
    attn_chan_kernel<<<G * 256, 256, 0, stream>>>(area, cstr);
    gemm_proj8<<<G * 48, 512, 0, stream>>>(area + 7 * (size_t)cstr, wpt, b_proj,
                                           out + b0 * S3);
  }
}

// Round 13
// 508.211 us; speedup vs baseline: 1.1651x; 1.0706x over previous
//
#include <hip/hip_runtime.h>

typedef _Float16 f16;
typedef f16  f16x8 __attribute__((ext_vector_type(8)));
typedef float f32x4 __attribute__((ext_vector_type(4)));

#define S3 3145728LL   // per-batch per-component elems (12*256*16*64 = 4096*768)

__device__ __forceinline__ f32x4 mm(f16x8 a, f16x8 b, f32x4 c) {
  return __builtin_amdgcn_mfma_f32_16x16x32_f16(a, b, c, 0, 0, 0);
}
__device__ __forceinline__ void BAR() { asm volatile("s_barrier" ::: "memory"); }

// epilogue LDS swizzle for [128][128] f16 tile
__device__ __forceinline__ int esw(int t, int col) {
  return t * 128 + ((((col >> 3) ^ ((t ^ (t >> 3)) & 7)) << 3) | (col & 7));
}
// swizzle for [256][64] f16 tile (attn_spat O staging)
__device__ __forceinline__ int oesw(int t, int col) {
  return t * 64 + ((((col >> 3) ^ (t & 7)) << 3) | (col & 7));
}

// ---------------- transpose + fp32->fp16 convert: out[Cc][R] = in[R][Cc] ----
__global__ void cvt_T_kernel(const float* __restrict__ in, f16* __restrict__ out,
                             int R, int Cc) {
  __shared__ float tile[32][33];
  int tc = blockIdx.x, tr = blockIdx.y;
  int lr = threadIdx.x & 31, lw = threadIdx.x >> 5;
  int c0 = tc * 32, r0 = tr * 32;
#pragma unroll
  for (int i = 0; i < 4; i++)
    tile[lw + 8 * i][lr] = in[(size_t)(r0 + lw + 8 * i) * Cc + c0 + lr];
  __syncthreads();
#pragma unroll
  for (int i = 0; i < 4; i++)
    out[(size_t)(c0 + lw + 8 * i) * R + r0 + lr] = (f16)tile[lr][lw + 8 * i];
}

// ---------------- x fp32 -> f16 (NT reads: x is never re-read) -------------
__global__ void cvt_x_kernel(const float* __restrict__ in, f16* __restrict__ out) {
  size_t i = ((size_t)blockIdx.x * 256 + threadIdx.x) * 8;
  f32x4 a = __builtin_nontemporal_load((const f32x4*)(in + i));
  f32x4 b = __builtin_nontemporal_load((const f32x4*)(in + i + 4));
  f16x8 o;
#pragma unroll
  for (int j = 0; j < 4; j++) { o[j] = (f16)a[j]; o[4 + j] = (f16)b[j]; }
  *(f16x8*)(out + i) = o;
}

// =================== QKV GEMM: 128x128 tile, BK=64, 64KB LDS ================
#define QST_A(c, q, kt) __builtin_amdgcn_global_load_lds( \
    (const __attribute__((address_space(1))) void*)(aSrc + (size_t)(q) * 24576 + (size_t)(kt) * 64), \
    (__attribute__((address_space(3))) void*)((char*)lds + (c) * 32768 + (q) * 1024 * 4 + wave * 1024), 16, 0, 0)
#define QST_B(c, q, kt) __builtin_amdgcn_global_load_lds( \
    (const __attribute__((address_space(1))) void*)(bSrc + (size_t)(q) * 24576 + (size_t)(kt) * 64), \
    (__attribute__((address_space(3))) void*)((char*)lds + 16384 + (c) * 32768 + (q) * 1024 * 4 + wave * 1024), 16, 0, 0)

__global__ __launch_bounds__(256, 2) void gemm_qkvT(
    const f16* __restrict__ A, const f16* __restrict__ Bt,
    f16* __restrict__ area, long long cstr_) {
  __shared__ f16 lds[32768];   // 64KB: 2 x (A 16KB | B 16KB); epilogue reuses 32KB
  size_t cstr = (size_t)cstr_;
  int id  = blockIdx.x;
  int cpx = gridDim.x >> 3;
  int id2 = (id & 7) * cpx + (id >> 3);       // XCD swizzle (grid % 8 == 0)
  int sr = id2 / 288, rr = id2 % 288;
  int bm = sr * 8 + (rr & 7), bn = rr >> 3;   // bm 0..G*32-1, bn 0..35

  int tid = threadIdx.x;
  int wave = tid >> 6, lane = tid & 63;
  int l16 = lane & 15, lq = lane >> 4;
  int wr = wave >> 1, wc = wave & 1;          // 2 x 2 wave grid
  int l7 = l16 & 7;
  int cb0 = ((lq) ^ l7) << 4;
  int cb1 = ((4 + lq) ^ l7) << 4;

  const f16* aSrc = A  + (size_t)(bm * 128 + (tid >> 3)) * 768 +
                    (((tid & 7) ^ ((tid >> 3) & 7)) << 3);
  const f16* bSrc = Bt + (size_t)(bn * 128 + (tid >> 3)) * 768 +
                    (((tid & 7) ^ ((tid >> 3) & 7)) << 3);

  f32x4 zz = {0.f, 0.f, 0.f, 0.f};
  f32x4 acc[4][4];
#pragma unroll
  for (int m = 0; m < 4; m++)
#pragma unroll
    for (int n = 0; n < 4; n++) acc[m][n] = zz;

#pragma unroll
  for (int q = 0; q < 4; q++) { QST_A(0, q, 0); }
#pragma unroll
  for (int q = 0; q < 4; q++) { QST_B(0, q, 0); }
#pragma unroll
  for (int q = 0; q < 4; q++) { QST_A(1, q, 1); }
#pragma unroll
  for (int q = 0; q < 4; q++) { QST_B(1, q, 1); }
  asm volatile("s_waitcnt vmcnt(8)" ::: "memory");
  BAR();

  f16x8 af[4][2], bf[4][2];
#pragma unroll 2
  for (int t = 0; t < 12; ++t) {
    int c = t & 1;
    const char* ab = (const char*)lds + c * 32768;
    const char* bb = ab + 16384;
    int rA = wr * 64 + l16;
    int rB = wc * 64 + l16;
#pragma unroll
    for (int mf = 0; mf < 4; mf++) {
      af[mf][0] = *(const f16x8*)(ab + (rA + mf * 16) * 128 + cb0);
      af[mf][1] = *(const f16x8*)(ab + (rA + mf * 16) * 128 + cb1);
    }
#pragma unroll
    for (int nf = 0; nf < 4; nf++) {
      bf[nf][0] = *(const f16x8*)(bb + (rB + nf * 16) * 128 + cb0);
      bf[nf][1] = *(const f16x8*)(bb + (rB + nf * 16) * 128 + cb1);
    }
    asm volatile("s_waitcnt lgkmcnt(0)" ::: "memory");
    BAR();
    if (t < 10) {
#pragma unroll
      for (int q = 0; q < 4; q++) { QST_A(c, q, t + 2); }
#pragma unroll
      for (int q = 0; q < 4; q++) { QST_B(c, q, t + 2); }
    }
    __builtin_amdgcn_s_setprio(1);
#pragma unroll
    for (int ks = 0; ks < 2; ks++)
#pragma unroll
      for (int mf = 0; mf < 4; mf++)
#pragma unroll
        for (int nf = 0; nf < 4; nf++)
          acc[mf][nf] = mm(af[mf][ks], bf[nf][ks], acc[mf][nf]);
    __builtin_amdgcn_s_setprio(0);
    if (t < 10) asm volatile("s_waitcnt vmcnt(8)" ::: "memory");
    else        asm volatile("s_waitcnt vmcnt(0)" ::: "memory");
    BAR();
  }

  // ---- coalesced LDS epilogue (32KB [128][128] C-tile) ----
  int s  = bn / 6;
  int h0 = (bn % 6) * 2;
  size_t comp;
  if (s == 0) comp = 0; else if (s == 1) comp = 1; else if (s == 2) comp = 3;
  else if (s == 3) comp = 4; else if (s == 4) comp = 2; else comp = 5;
  int g = (bm * 128) >> 12;
  size_t base = comp * cstr + (size_t)g * S3;
  int n0 = (bm & 31) * 8;

  __syncthreads();
#pragma unroll
  for (int mi = 0; mi < 4; mi++)
#pragma unroll
    for (int ni = 0; ni < 4; ni++)
#pragma unroll
      for (int r = 0; r < 4; r++) {
        int t = wr * 64 + mi * 16 + lq * 4 + r;
        int col = wc * 64 + ni * 16 + l16;
        lds[esw(t, col)] = (f16)acc[mi][ni][r];
      }
  __syncthreads();

  if (s < 2) {            // qc/kc [h][n][c][d]
#pragma unroll
    for (int i = 0; i < 4; i++) {
      int u = wave * 4 + i;
      int hl = u >> 3, j16 = u & 7;
#pragma unroll
      for (int half = 0; half < 2; half++) {
        int e0 = half * 512 + lane * 8;
        int cc = e0 >> 6, d0 = e0 & 63;
        f16x8 v = *(const f16x8*)&lds[esw(j16 * 16 + cc, hl * 64 + d0)];
        __builtin_nontemporal_store(v, (f16x8*)&area[base +
            (size_t)(h0 + hl) * 262144 + (size_t)(n0 + j16) * 1024 + e0]);
      }
    }
  } else if (s < 4) {     // qs/ks [h][c][n][d]
#pragma unroll
    for (int i = 0; i < 8; i++) {
      int u = wave * 8 + i;
      int hl = u >> 4, cc = u & 15;
      int e = lane * 8;
      int nl = e >> 6, d0 = e & 63;
      f16x8 v = *(const f16x8*)&lds[esw(nl * 16 + cc, hl * 64 + d0)];
      __builtin_nontemporal_store(v, (f16x8*)&area[base +
          (size_t)((h0 + hl) * 16 + cc) * 16384 + (size_t)n0 * 64 + e]);
    }
  } else if (s == 4) {    // vc [h][n][d][c]
#pragma unroll
    for (int i = 0; i < 4; i++) {
      int u = wave * 4 + i;
      int hl = u >> 3, j8 = u & 7;
#pragma unroll
      for (int half = 0; half < 2; half++) {
        int e0 = half * 512 + lane * 8;
        int d0 = e0 >> 4, cb = e0 & 15;
        f16x8 v;
#pragma unroll
        for (int j = 0; j < 8; j++)
          v[j] = lds[esw(j8 * 16 + cb + j, hl * 64 + d0)];
        __builtin_nontemporal_store(v, (f16x8*)&area[base +
            (size_t)((h0 + hl) * 256 + n0 + j8) * 1024 + e0]);
      }
    }
  } else {                // vs blocked [h][c][nb8][d][nl8]
#pragma unroll
    for (int i = 0; i < 8; i++) {
      int u = wave * 8 + i;
      int hl = u >> 4, cc = u & 15;
      int e = lane * 8;
      int d0 = e >> 3;
      f16x8 v;
#pragma unroll
      for (int j = 0; j < 8; j++)
        v[j] = lds[esw(j * 16 + cc, hl * 64 + d0)];
      __builtin_nontemporal_store(v, (f16x8*)&area[base +
          ((size_t)((h0 + hl) * 16 + cc) * 32 + (bm & 31)) * 512 + e]);
    }
  }
}

// ---------- proj GEMM: 128x128 tile, same pipeline, out = A*wpt^T + bias ----
__global__ __launch_bounds__(256, 2) void gemm_projT(
    const f16* __restrict__ A,       // prod [G*4096][768] (comp3)
    const f16* __restrict__ Bt,      // wpt [768][768]
    const float* __restrict__ bias, float* __restrict__ Cout) {
  __shared__ f16 lds[32768];
  int id  = blockIdx.x;
  int cpx = gridDim.x >> 3;
  int id2 = (id & 7) * cpx + (id >> 3);       // grid = G*192, %8==0
  int sr = id2 / 48, rr = id2 % 48;
  int bm = sr * 8 + (rr & 7), bn = rr >> 3;   // bm 0..G*32-1, bn 0..5

  int tid = threadIdx.x;
  int wave = tid >> 6, lane = tid & 63;
  int l16 = lane & 15, lq = lane >> 4;
  int wr = wave >> 1, wc = wave & 1;
  int l7 = l16 & 7;
  int cb0 = ((lq) ^ l7) << 4;
  int cb1 = ((4 + lq) ^ l7) << 4;

  const f16* aSrc = A  + (size_t)(bm * 128 + (tid >> 3)) * 768 +
                    (((tid & 7) ^ ((tid >> 3) & 7)) << 3);
  const f16* bSrc = Bt + (size_t)(bn * 128 + (tid >> 3)) * 768 +
                    (((tid & 7) ^ ((tid >> 3) & 7)) << 3);

  f32x4 zz = {0.f, 0.f, 0.f, 0.f};
  f32x4 acc[4][4];
#pragma unroll
  for (int m = 0; m < 4; m++)
#pragma unroll
    for (int n = 0; n < 4; n++) acc[m][n] = zz;

#pragma unroll
  for (int q = 0; q < 4; q++) { QST_A(0, q, 0); }
#pragma unroll
  for (int q = 0; q < 4; q++) { QST_B(0, q, 0); }
#pragma unroll
  for (int q = 0; q < 4; q++) { QST_A(1, q, 1); }
#pragma unroll
  for (int q = 0; q < 4; q++) { QST_B(1, q, 1); }
  asm volatile("s_waitcnt vmcnt(8)" ::: "memory");
  BAR();

  f16x8 af[4][2], bf[4][2];
#pragma unroll 2
  for (int t = 0; t < 12; ++t) {
    int c = t & 1;
    const char* ab = (const char*)lds + c * 32768;
    const char* bb = ab + 16384;
    int rA = wr * 64 + l16;
    int rB = wc * 64 + l16;
#pragma unroll
    for (int mf = 0; mf < 4; mf++) {
      af[mf][0] = *(const f16x8*)(ab + (rA + mf * 16) * 128 + cb0);
      af[mf][1] = *(const f16x8*)(ab + (rA + mf * 16) * 128 + cb1);
    }
#pragma unroll
    for (int nf = 0; nf < 4; nf++) {
      bf[nf][0] = *(const f16x8*)(bb + (rB + nf * 16) * 128 + cb0);
      bf[nf][1] = *(const f16x8*)(bb + (rB + nf * 16) * 128 + cb1);
    }
    asm volatile("s_waitcnt lgkmcnt(0)" ::: "memory");
    BAR();
    if (t < 10) {
#pragma unroll
      for (int q = 0; q < 4; q++) { QST_A(c, q, t + 2); }
#pragma unroll
      for (int q = 0; q < 4; q++) { QST_B(c, q, t + 2); }
    }
    __builtin_amdgcn_s_setprio(1);
#pragma unroll
    for (int ks = 0; ks < 2; ks++)
#pragma unroll
      for (int mf = 0; mf < 4; mf++)
#pragma unroll
        for (int nf = 0; nf < 4; nf++)
          acc[mf][nf] = mm(af[mf][ks], bf[nf][ks], acc[mf][nf]);
    __builtin_amdgcn_s_setprio(0);
    if (t < 10) asm volatile("s_waitcnt vmcnt(8)" ::: "memory");
    else        asm volatile("s_waitcnt vmcnt(0)" ::: "memory");
    BAR();
  }

  // direct fp32 epilogue with bias
#pragma unroll
  for (int ni = 0; ni < 4; ni++) {
    int col = bn * 128 + wc * 64 + ni * 16 + l16;
    float bb = bias[col];
#pragma unroll
    for (int mi = 0; mi < 4; mi++) {
#pragma unroll
      for (int r = 0; r < 4; r++) {
        int row = bm * 128 + wr * 64 + mi * 16 + lq * 4 + r;
        __builtin_nontemporal_store(acc[mi][ni][r] + bb,
                                    &Cout[(size_t)row * 768 + col]);
      }
    }
  }
}

// ---------------- spatial attention: per (g,h,c); xs OUT = [n][h][c][d] -----
__global__ __launch_bounds__(512) void attn_spat_kernel(f16* __restrict__ area,
                                                        long long cstr_) {
  size_t cstr = (size_t)cstr_;
  int blk = blockIdx.x;
  int g = blk / 192, rem = blk % 192;
  int h = rem >> 4, c = rem & 15;
  size_t goff = (size_t)g * S3;
  const f16* qs = area + 3 * cstr + goff + (size_t)((h * 16 + c) * 256) * 64;
  const f16* ks = area + 4 * cstr + goff + (size_t)((h * 16 + c) * 256) * 64;
  const f16* vsb = area + 5 * cstr + goff + (size_t)(h * 16 + c) * 16384; // [nb8][d][nl8]
  f16* xsn = area + 6 * cstr + goff;   // [n][h][c][d]

  int tid = threadIdx.x;
  int wave = tid >> 6, lane = tid & 63;
  int l16 = lane & 15, lq = lane >> 4;
  __shared__ f16 plds[8][32][40];
  __shared__ f16 osm[16384];          // [256][64] swizzled (oesw)

  f32x4 zz = {0.f, 0.f, 0.f, 0.f};
  f16x8 aq[2][2];
#pragma unroll
  for (int m = 0; m < 2; m++)
#pragma unroll
    for (int kd = 0; kd < 2; kd++)
      aq[m][kd] = *(const f16x8*)&qs[(size_t)(wave * 32 + m * 16 + l16) * 64 + kd * 32 + lq * 8];

  f32x4 o[2][4];
  float mrow[2][4], lrow[2][4];
#pragma unroll
  for (int m = 0; m < 2; m++) {
#pragma unroll
    for (int n = 0; n < 4; n++) o[m][n] = zz;
#pragma unroll
    for (int r = 0; r < 4; r++) { mrow[m][r] = -1e30f; lrow[m][r] = 0.f; }
  }

  for (int kc = 0; kc < 8; kc++) {
    int k0 = kc * 32;
    f16x8 bk00 = *(const f16x8*)&ks[(size_t)(k0 + l16) * 64 + lq * 8];
    f16x8 bk01 = *(const f16x8*)&ks[(size_t)(k0 + l16) * 64 + 32 + lq * 8];
    f16x8 bk10 = *(const f16x8*)&ks[(size_t)(k0 + 16 + l16) * 64 + lq * 8];
    f16x8 bk11 = *(const f16x8*)&ks[(size_t)(k0 + 16 + l16) * 64 + 32 + lq * 8];
    f32x4 st[2][2];
#pragma unroll
    for (int m = 0; m < 2; m++) {
      st[m][0] = mm(aq[m][1], bk01, mm(aq[m][0], bk00, zz));
      st[m][1] = mm(aq[m][1], bk11, mm(aq[m][0], bk10, zz));
    }
#pragma unroll
    for (int m = 0; m < 2; m++) {
#pragma unroll
      for (int r = 0; r < 4; r++) {
        float s0 = st[m][0][r] * 0.125f, s1 = st[m][1][r] * 0.125f;
        float t = fmaxf(s0, s1);
        t = fmaxf(t, __shfl_xor(t, 1));
        t = fmaxf(t, __shfl_xor(t, 2));
        t = fmaxf(t, __shfl_xor(t, 4));
        t = fmaxf(t, __shfl_xor(t, 8));
        float mold = mrow[m][r];
        float mnew = fmaxf(mold, t);
        float fac  = __expf(mold - mnew);
        mrow[m][r] = mnew;
        float p0 = __expf(s0 - mnew), p1 = __expf(s1 - mnew);
        lrow[m][r] = lrow[m][r] * fac + p0 + p1;
        o[m][0][r] *= fac; o[m][1][r] *= fac; o[m][2][r] *= fac; o[m][3][r] *= fac;
        int prow = m * 16 + lq * 4 + r;
        plds[wave][prow][l16]      = (f16)p0;
        plds[wave][prow][16 + l16] = (f16)p1;
      }
    }
    f16x8 ap0 = *(const f16x8*)&plds[wave][l16][lq * 8];
    f16x8 ap1 = *(const f16x8*)&plds[wave][16 + l16][lq * 8];
#pragma unroll
    for (int n = 0; n < 4; n++) {
      f16x8 bv = *(const f16x8*)&vsb[((k0 >> 3) + lq) * 512 + (n * 16 + l16) * 8];
      o[0][n] = mm(ap0, bv, o[0][n]);
      o[1][n] = mm(ap1, bv, o[1][n]);
    }
  }
#pragma unroll
  for (int m = 0; m < 2; m++)
#pragma unroll
    for (int r = 0; r < 4; r++) {
      float l = lrow[m][r];
      l += __shfl_xor(l, 1);
      l += __shfl_xor(l, 2);
      l += __shfl_xor(l, 4);
      l += __shfl_xor(l, 8);
      lrow[m][r] = 1.0f / l;
    }
#pragma unroll
  for (int m = 0; m < 2; m++)
#pragma unroll
    for (int n = 0; n < 4; n++)
#pragma unroll
      for (int r = 0; r < 4; r++) {
        int row = wave * 32 + m * 16 + lq * 4 + r;
        osm[oesw(row, n * 16 + l16)] = (f16)(o[m][n][r] * lrow[m][r]);
      }
  __syncthreads();
  size_t hc64 = (size_t)(h * 16 + c) * 64;
#pragma unroll
  for (int i = 0; i < 4; i++) {
    int row = i * 64 + (tid >> 3);
    int dp  = (tid & 7) * 8;
    f16x8 v = *(const f16x8*)&osm[oesw(row, dp)];
    __builtin_nontemporal_store(v, (f16x8*)&xsn[(size_t)row * 12288 + hc64 + dp]);
  }
}

// ---------------- channel attention + combine: per (g,n), 12 heads ----------
// xs IN = [n][h][c][d] (comp6); prod OUT = [n][h][c][d] (comp3, qs dead).
__global__ __launch_bounds__(256) void attn_chan_kernel(f16* __restrict__ area,
                                                        long long cstr_) {
  size_t cstr = (size_t)cstr_;
  int blk = blockIdx.x;
  int g = blk >> 8, n = blk & 255;
  size_t goff = (size_t)g * S3;
  int tid = threadIdx.x;
  int wave = tid >> 6, lane = tid & 63;
  int l16 = lane & 15, lq = lane >> 4;
  __shared__ f16 xsl[12288];
  __shared__ f16 prl[12288];
  __shared__ f16 plds[4][16][40];

  const f16* xsn = area + 6 * cstr + goff + (size_t)n * 12288;
#pragma unroll
  for (int i = 0; i < 6; i++) {
    int seg = wave * 6 + i;
    __builtin_amdgcn_global_load_lds(
        (const __attribute__((address_space(1))) void*)(xsn + seg * 512 + lane * 8),
        (__attribute__((address_space(3))) void*)((char*)xsl + seg * 1024), 16, 0, 0);
  }
  if (lane < 16) {
#pragma unroll
    for (int j = 0; j < 16; j++) plds[wave][lane][16 + j] = (f16)0.f;
  }
  asm volatile("s_waitcnt vmcnt(0)" ::: "memory");
  __syncthreads();

  f32x4 zz = {0.f, 0.f, 0.f, 0.f};
  for (int hi = 0; hi < 3; hi++) {
    int h = wave + hi * 4;
    const f16* q = area + 0 * cstr + goff + (size_t)((h * 256 + n) * 16) * 64;
    const f16* k = area + 1 * cstr + goff + (size_t)((h * 256 + n) * 16) * 64;
    const f16* v = area + 2 * cstr + goff + (size_t)((h * 256 + n) * 64) * 16; // [d][c]
    f16x8 a0 = *(const f16x8*)&q[l16 * 64 + lq * 8];
    f16x8 a1 = *(const f16x8*)&q[l16 * 64 + 32 + lq * 8];
    f16x8 b0 = *(const f16x8*)&k[l16 * 64 + lq * 8];
    f16x8 b1 = *(const f16x8*)&k[l16 * 64 + 32 + lq * 8];
    f32x4 s = mm(a1, b1, mm(a0, b0, zz));
    float p[4];
#pragma unroll
    for (int r = 0; r < 4; r++) {
      float t = s[r] * 0.125f;
      float mx = t;
      mx = fmaxf(mx, __shfl_xor(mx, 1));
      mx = fmaxf(mx, __shfl_xor(mx, 2));
      mx = fmaxf(mx, __shfl_xor(mx, 4));
      mx = fmaxf(mx, __shfl_xor(mx, 8));
      float e = __expf(t - mx);
      float sum = e;
      sum += __shfl_xor(sum, 1);
      sum += __shfl_xor(sum, 2);
      sum += __shfl_xor(sum, 4);
      sum += __shfl_xor(sum, 8);
      p[r] = e / sum;
    }
#pragma unroll
    for (int r = 0; r < 4; r++)
      plds[wave][lq * 4 + r][l16] = (f16)p[r];
    f16x8 ap = *(const f16x8*)&plds[wave][l16][lq * 8];
#pragma unroll
    for (int nt = 0; nt < 4; nt++) {
      f16x8 bv = *(const f16x8*)&v[(nt * 16 + l16) * 16 + lq * 8];
      f32x4 o = mm(ap, bv, zz);
#pragma unroll
      for (int r = 0; r < 4; r++) {
        int cq = lq * 4 + r, d = nt * 16 + l16;
        int idx = h * 1024 + cq * 64 + d;
        float xsv = (float)xsl[idx];
        prl[idx] = (f16)(o[r] * xsv);
      }
    }
  }
  __syncthreads();
  f16* prod = area + 3 * cstr + goff + (size_t)n * 12288;
#pragma unroll
  for (int i = 0; i < 6; i++) {
    f16x8 v = *(const f16x8*)&prl[i * 2048 + tid * 8];
    __builtin_nontemporal_store(v, (f16x8*)&prod[i * 2048 + tid * 8]);
  }
}

// ---------------- host ------------------------------------------------------
extern "C" void kernel_launch(void* const* d_in, const int* in_sizes, int n_in,
                              void* d_out, int out_size, void* d_ws, size_t ws_size,
                              hipStream_t stream) {
  const float* x      = (const float*)d_in[0];
  const float* w_qkv  = (const float*)d_in[1];
  const float* w_proj = (const float*)d_in[2];
  const float* b_proj = (const float*)d_in[3];
  float* out = (float*)d_out;
  f16* ws = (f16*)d_ws;

  const size_t W16T = 4608ull * 768;
  const size_t WPT  = 768ull * 768;
  f16* w16t = ws;
  f16* wpt  = ws + W16T;
  f16* area = wpt + WPT;

  // 7-component plan: 0 qc, 1 kc, 2 vc, 3 qs->prod, 4 ks, 5 vs, 6 x16->xs
  int G = 8;  // batches per chunk; shrink until scratch fits
  while (G > 1 && (W16T + WPT + 7ull * G * S3) * 2 > ws_size) G >>= 1;
  int nch = 8 / G;
  long long cstr = (long long)G * S3;
  f16* x16 = area + 6 * (size_t)cstr;   // aliased with xs (dead before attn_spat)

  cvt_T_kernel<<<dim3(144, 24), 256, 0, stream>>>(w_qkv, w16t, 768, 4608);
  cvt_T_kernel<<<dim3(24, 24), 256, 0, stream>>>(w_proj, wpt, 768, 768);

  for (int ch = 0; ch < nch; ch++) {
    size_t b0 = (size_t)ch * G;
    cvt_x_kernel<<<G * 1536, 256, 0, stream>>>(x + b0 * S3, x16);
    gemm_qkvT<<<G * 1152, 256, 0, stream>>>(x16, w16t, area, cstr);
    attn_spat_kernel<<<G * 192, 512, 0, stream>>>(area, cstr);
    attn_chan_kernel<<<G * 256, 256, 0, stream>>>(area, cstr);
    gemm_projT<<<G * 192, 256, 0, stream>>>(area + 3 * (size_t)cstr, wpt, b_proj,
                                            out + b0 * S3);
  }
}

// Round 14
// 504.117 us; speedup vs baseline: 1.1745x; 1.0081x over previous
//
#include <hip/hip_runtime.h>

typedef _Float16 f16;
typedef f16  f16x8 __attribute__((ext_vector_type(8)));
typedef float f32x4 __attribute__((ext_vector_type(4)));

#define S3 3145728LL   // per-batch per-component elems (12*256*16*64 = 4096*768)

__device__ __forceinline__ f32x4 mm(f16x8 a, f16x8 b, f32x4 c) {
  return __builtin_amdgcn_mfma_f32_16x16x32_f16(a, b, c, 0, 0, 0);
}
__device__ __forceinline__ void BAR() { asm volatile("s_barrier" ::: "memory"); }
#define LGKM0() do { asm volatile("s_waitcnt lgkmcnt(0)" ::: "memory"); \
                     __builtin_amdgcn_sched_barrier(0); } while (0)

// LDS swizzle for [256][256] f16 C-tile (qkv epilogue)
__device__ __forceinline__ int esw256(int t, int col) {
  return t * 256 + ((((col >> 3) ^ ((t ^ (t >> 3)) & 7)) << 3) | (col & 7));
}
// swizzle for [256][64] f16 tile (attn_spat O staging)
__device__ __forceinline__ int oesw(int t, int col) {
  return t * 64 + ((((col >> 3) ^ (t & 7)) << 3) | (col & 7));
}

// ---------------- transpose + fp32->fp16 convert: out[Cc][R] = in[R][Cc] ----
__global__ void cvt_T_kernel(const float* __restrict__ in, f16* __restrict__ out,
                             int R, int Cc) {
  __shared__ float tile[32][33];
  int tc = blockIdx.x, tr = blockIdx.y;
  int lr = threadIdx.x & 31, lw = threadIdx.x >> 5;
  int c0 = tc * 32, r0 = tr * 32;
#pragma unroll
  for (int i = 0; i < 4; i++)
    tile[lw + 8 * i][lr] = in[(size_t)(r0 + lw + 8 * i) * Cc + c0 + lr];
  __syncthreads();
#pragma unroll
  for (int i = 0; i < 4; i++)
    out[(size_t)(c0 + lw + 8 * i) * R + r0 + lr] = (f16)tile[lr][lw + 8 * i];
}

// ---------------- x fp32 -> f16 (NT reads: x is never re-read) -------------
__global__ void cvt_x_kernel(const float* __restrict__ in, f16* __restrict__ out) {
  size_t i = ((size_t)blockIdx.x * 256 + threadIdx.x) * 8;
  f32x4 a = __builtin_nontemporal_load((const f32x4*)(in + i));
  f32x4 b = __builtin_nontemporal_load((const f32x4*)(in + i + 4));
  f16x8 o;
#pragma unroll
  for (int j = 0; j < 4; j++) { o[j] = (f16)a[j]; o[4 + j] = (f16)b[j]; }
  *(f16x8*)(out + i) = o;
}

// ============ QKV GEMM: 256x256 tile, BK=64, 8-wave, 8-phase pipeline =======
// LDS 128KB = 2 dbuf x (A 32KB | B 32KB). Quarter = 64 rows x 64 cols = 8KB =
// 512 threads x 16B (1 gload_lds each). Staging stream (tile t, dbuf c=t&1):
//   P1: A1,A3 of t+1 -> dbuf c^1      (A1/A3 of t-1... freed at prior P3)
//   P2: A0,A2 of t+2 -> dbuf c        (freed by P1's af reads)
//   P3: B0,B1 of t+2 -> dbuf c        (freed by P2's b23 reads)
//   P4: B2,B3 of t+2 -> dbuf c
// Single vmcnt(6) at each P4 guarantees all loads issued <= prev-P1 landed
// => next tile fully resident. Tail (t>=10): vmcnt(0).
#define P8_A(c, q, kt) __builtin_amdgcn_global_load_lds( \
    (const __attribute__((address_space(1))) void*)(aSrc + (size_t)(q) * 49152 + (size_t)(kt) * 64), \
    (__attribute__((address_space(3))) void*)((char*)lds + (c) * 65536 + (q) * 8192 + tid * 16), 16, 0, 0)
#define P8_B(c, q, kt) __builtin_amdgcn_global_load_lds( \
    (const __attribute__((address_space(1))) void*)(bSrc + (size_t)(q) * 49152 + (size_t)(kt) * 64), \
    (__attribute__((address_space(3))) void*)((char*)lds + (c) * 65536 + 32768 + (q) * 8192 + tid * 16), 16, 0, 0)

__global__ __launch_bounds__(512, 2) void gemm_qkv8p(
    const f16* __restrict__ A, const f16* __restrict__ Bt,
    f16* __restrict__ area, long long cstr_) {
  __shared__ f16 lds[65536];   // 128KB
  size_t cstr = (size_t)cstr_;
  int id  = blockIdx.x;
  int cpx = gridDim.x >> 3;
  int id2 = (id & 7) * cpx + (id >> 3);       // XCD swizzle (grid % 8 == 0)
  int sr = id2 / 144, rr = id2 % 144;
  int bm = sr * 8 + (rr & 7), bn = rr >> 3;   // bm 0..G*16-1, bn 0..17

  int tid = threadIdx.x;
  int wave = tid >> 6, lane = tid & 63;
  int l16 = lane & 15, lq = lane >> 4;
  int wr = wave >> 2, wc = wave & 3;          // 2 x 4 wave grid
  int l7 = l16 & 7;
  int cb0 = ((lq) ^ l7) << 4;                 // granule ks=0 (byte offset)
  int cb1 = ((4 + lq) ^ l7) << 4;             // granule ks=1

  // pre-swizzled global sources (linear LDS dest; src col granule ^= row&7)
  const f16* aSrc = A  + (size_t)(bm * 256 + (tid >> 3)) * 768 +
                    (((tid & 7) ^ ((tid >> 3) & 7)) << 3);
  const f16* bSrc = Bt + (size_t)(bn * 256 + (tid >> 3)) * 768 +
                    (((tid & 7) ^ ((tid >> 3) & 7)) << 3);

  f32x4 zz = {0.f, 0.f, 0.f, 0.f};
  f32x4 acc[8][4];
#pragma unroll
  for (int m = 0; m < 8; m++)
#pragma unroll
    for (int n = 0; n < 4; n++) acc[m][n] = zz;

  // prologue: tile0 all 8 quarters + tile1 {A0,A2,B0..B3}; vmcnt(6) -> tile0 in
  P8_A(0, 0, 0); P8_A(0, 1, 0); P8_A(0, 2, 0); P8_A(0, 3, 0);
  P8_B(0, 0, 0); P8_B(0, 1, 0); P8_B(0, 2, 0); P8_B(0, 3, 0);
  P8_A(1, 0, 1); P8_A(1, 2, 1);
  P8_B(1, 0, 1); P8_B(1, 1, 1); P8_B(1, 2, 1); P8_B(1, 3, 1);
  asm volatile("s_waitcnt vmcnt(6)" ::: "memory");
  BAR();

  f16x8 af[4][2], ag[4][2], b01[2][2], b23[2][2];
#pragma unroll 2
  for (int t = 0; t < 12; ++t) {
    int c = t & 1, o = c ^ 1;
    const char* ab = (const char*)lds + c * 65536;
    const char* bb = ab + 32768;
    int rA = wr * 128 + l16;
    int rB = wc * 64 + l16;

    // ---- P1: read af + b01 -> C(M0-3, N0-1); stage A1,A3 of t+1 ----
#pragma unroll
    for (int mf = 0; mf < 4; mf++) {
      af[mf][0] = *(const f16x8*)(ab + (rA + mf * 16) * 128 + cb0);
      af[mf][1] = *(const f16x8*)(ab + (rA + mf * 16) * 128 + cb1);
    }
#pragma unroll
    for (int nf = 0; nf < 2; nf++) {
      b01[nf][0] = *(const f16x8*)(bb + (rB + nf * 16) * 128 + cb0);
      b01[nf][1] = *(const f16x8*)(bb + (rB + nf * 16) * 128 + cb1);
    }
    if (t < 11) { P8_A(o, 1, t + 1); P8_A(o, 3, t + 1); }
    BAR(); LGKM0();
    __builtin_amdgcn_s_setprio(1);
#pragma unroll
    for (int ks = 0; ks < 2; ks++)
#pragma unroll
      for (int mf = 0; mf < 4; mf++)
#pragma unroll
        for (int nf = 0; nf < 2; nf++)
          acc[mf][nf] = mm(af[mf][ks], b01[nf][ks], acc[mf][nf]);
    __builtin_amdgcn_s_setprio(0);
    BAR();

    // ---- P2: read b23 -> C(M0-3, N2-3); stage A0,A2 of t+2 ----
#pragma unroll
    for (int nf = 0; nf < 2; nf++) {
      b23[nf][0] = *(const f16x8*)(bb + (rB + 32 + nf * 16) * 128 + cb0);
      b23[nf][1] = *(const f16x8*)(bb + (rB + 32 + nf * 16) * 128 + cb1);
    }
    if (t < 10) { P8_A(c, 0, t + 2); P8_A(c, 2, t + 2); }
    BAR(); LGKM0();
    __builtin_amdgcn_s_setprio(1);
#pragma unroll
    for (int ks = 0; ks < 2; ks++)
#pragma unroll
      for (int mf = 0; mf < 4; mf++)
#pragma unroll
        for (int nf = 0; nf < 2; nf++)
          acc[mf][2 + nf] = mm(af[mf][ks], b23[nf][ks], acc[mf][2 + nf]);
    __builtin_amdgcn_s_setprio(0);
    BAR();

    // ---- P3: read ag -> C(M4-7, N0-1); stage B0,B1 of t+2 ----
#pragma unroll
    for (int mf = 0; mf < 4; mf++) {
      ag[mf][0] = *(const f16x8*)(ab + (rA + 64 + mf * 16) * 128 + cb0);
      ag[mf][1] = *(const f16x8*)(ab + (rA + 64 + mf * 16) * 128 + cb1);
    }
    if (t < 10) { P8_B(c, 0, t + 2); P8_B(c, 1, t + 2); }
    BAR(); LGKM0();
    __builtin_amdgcn_s_setprio(1);
#pragma unroll
    for (int ks = 0; ks < 2; ks++)
#pragma unroll
      for (int mf = 0; mf < 4; mf++)
#pragma unroll
        for (int nf = 0; nf < 2; nf++)
          acc[4 + mf][nf] = mm(ag[mf][ks], b01[nf][ks], acc[4 + mf][nf]);
    __builtin_amdgcn_s_setprio(0);
    BAR();

    // ---- P4: no reads -> C(M4-7, N2-3); stage B2,B3 of t+2; vmcnt ----
    if (t < 10) { P8_B(c, 2, t + 2); P8_B(c, 3, t + 2); }
    __builtin_amdgcn_s_setprio(1);
#pragma unroll
    for (int ks = 0; ks < 2; ks++)
#pragma unroll
      for (int mf = 0; mf < 4; mf++)
#pragma unroll
        for (int nf = 0; nf < 2; nf++)
          acc[4 + mf][2 + nf] = mm(ag[mf][ks], b23[nf][ks], acc[4 + mf][2 + nf]);
    __builtin_amdgcn_s_setprio(0);
    if (t < 10) asm volatile("s_waitcnt vmcnt(6)" ::: "memory");
    else        asm volatile("s_waitcnt vmcnt(0)" ::: "memory");
    BAR();
  }

  // ---- single-pass full-tile LDS epilogue (256x256, verified R7-R10) ----
  //  qc/kc [h][n][c][d]; qs/ks [h][c][n][d]; vc [h][n][d][c];
  //  vs BLOCKED [h][c][nb8 32][d 64][nl8 8] (matches R13 attn_spat).
  int s  = bn / 3;
  int h0 = (bn % 3) * 4;
  size_t comp;
  if (s == 0) comp = 0; else if (s == 1) comp = 1; else if (s == 2) comp = 3;
  else if (s == 3) comp = 4; else if (s == 4) comp = 2; else comp = 5;
  int g = bm >> 4;
  size_t base = comp * cstr + (size_t)g * S3;
  int n0 = (bm & 15) * 16;     // 16 tokens per tile

  __syncthreads();
#pragma unroll
  for (int mi = 0; mi < 8; mi++)
#pragma unroll
    for (int ni = 0; ni < 4; ni++)
#pragma unroll
      for (int r = 0; r < 4; r++) {
        int tl = wr * 128 + (mi >> 2) * 64 + (mi & 3) * 16 + lq * 4 + r;
        int col = wc * 64 + ni * 16 + l16;
        lds[esw256(tl, col)] = (f16)acc[mi][ni][r];
      }
  __syncthreads();

  // 64 units of 2KB (hl 0..3 x j16 0..15), 8 per wave.
#pragma unroll
  for (int i = 0; i < 8; i++) {
    int u = wave * 8 + i;
    int hl = u >> 4, j16 = u & 15;
    int h  = h0 + hl;
#pragma unroll
    for (int half = 0; half < 2; half++) {
      int e0 = half * 512 + lane * 8;
      f16x8 v;
      size_t dst;
      if (s < 2) {            // qc/kc: unit (hl, nloc=j16); e = c*64 + d
        int cc = e0 >> 6, d0 = e0 & 63;
        v = *(const f16x8*)&lds[esw256(j16 * 16 + cc, hl * 64 + d0)];
        dst = base + (size_t)h * 262144 + (size_t)(n0 + j16) * 1024 + e0;
      } else if (s < 4) {     // qs/ks: unit (hl, c=j16); e = nloc*64 + d
        int nl = e0 >> 6, d0 = e0 & 63;
        v = *(const f16x8*)&lds[esw256(nl * 16 + j16, hl * 64 + d0)];
        dst = base + (size_t)(h * 16 + j16) * 16384 + (size_t)n0 * 64 + e0;
      } else if (s == 4) {    // vc: unit (hl, nloc=j16); e = d*16 + c
        int d0 = e0 >> 4, cb = e0 & 15;
#pragma unroll
        for (int j = 0; j < 8; j++)
          v[j] = lds[esw256(j16 * 16 + cb + j, hl * 64 + d0)];
        dst = base + (size_t)(h * 256 + n0 + j16) * 1024 + e0;
      } else {                // vs blocked-8: unit (hl, c=j16); e = nbl*512+d*8+nl
        int d0 = (e0 >> 3) & 63, nbl = e0 >> 9;
#pragma unroll
        for (int j = 0; j < 8; j++)
          v[j] = lds[esw256((nbl * 8 + j) * 16 + j16, hl * 64 + d0)];
        dst = base + ((size_t)(h * 16 + j16) * 32 + (n0 >> 3) + nbl) * 512 +
              (e0 & 511);
      }
      __builtin_nontemporal_store(v, (f16x8*)&area[dst]);
    }
  }
}

// ---------- proj GEMM: 128x128 tile (unchanged from R13) --------------------
#define QST_A(c, q, kt) __builtin_amdgcn_global_load_lds( \
    (const __attribute__((address_space(1))) void*)(aSrc + (size_t)(q) * 24576 + (size_t)(kt) * 64), \
    (__attribute__((address_space(3))) void*)((char*)lds + (c) * 32768 + (q) * 1024 * 4 + wave * 1024), 16, 0, 0)
#define QST_B(c, q, kt) __builtin_amdgcn_global_load_lds( \
    (const __attribute__((address_space(1))) void*)(bSrc + (size_t)(q) * 24576 + (size_t)(kt) * 64), \
    (__attribute__((address_space(3))) void*)((char*)lds + 16384 + (c) * 32768 + (q) * 1024 * 4 + wave * 1024), 16, 0, 0)

__global__ __launch_bounds__(256, 2) void gemm_projT(
    const f16* __restrict__ A, const f16* __restrict__ Bt,
    const float* __restrict__ bias, float* __restrict__ Cout) {
  __shared__ f16 lds[32768];
  int id  = blockIdx.x;
  int cpx = gridDim.x >> 3;
  int id2 = (id & 7) * cpx + (id >> 3);
  int sr = id2 / 48, rr = id2 % 48;
  int bm = sr * 8 + (rr & 7), bn = rr >> 3;

  int tid = threadIdx.x;
  int wave = tid >> 6, lane = tid & 63;
  int l16 = lane & 15, lq = lane >> 4;
  int wr = wave >> 1, wc = wave & 1;
  int l7 = l16 & 7;
  int cb0 = ((lq) ^ l7) << 4;
  int cb1 = ((4 + lq) ^ l7) << 4;

  const f16* aSrc = A  + (size_t)(bm * 128 + (tid >> 3)) * 768 +
                    (((tid & 7) ^ ((tid >> 3) & 7)) << 3);
  const f16* bSrc = Bt + (size_t)(bn * 128 + (tid >> 3)) * 768 +
                    (((tid & 7) ^ ((tid >> 3) & 7)) << 3);

  f32x4 zz = {0.f, 0.f, 0.f, 0.f};
  f32x4 acc[4][4];
#pragma unroll
  for (int m = 0; m < 4; m++)
#pragma unroll
    for (int n = 0; n < 4; n++) acc[m][n] = zz;

#pragma unroll
  for (int q = 0; q < 4; q++) { QST_A(0, q, 0); }
#pragma unroll
  for (int q = 0; q < 4; q++) { QST_B(0, q, 0); }
#pragma unroll
  for (int q = 0; q < 4; q++) { QST_A(1, q, 1); }
#pragma unroll
  for (int q = 0; q < 4; q++) { QST_B(1, q, 1); }
  asm volatile("s_waitcnt vmcnt(8)" ::: "memory");
  BAR();

  f16x8 af[4][2], bf[4][2];
#pragma unroll 2
  for (int t = 0; t < 12; ++t) {
    int c = t & 1;
    const char* ab = (const char*)lds + c * 32768;
    const char* bb = ab + 16384;
    int rA = wr * 64 + l16;
    int rB = wc * 64 + l16;
#pragma unroll
    for (int mf = 0; mf < 4; mf++) {
      af[mf][0] = *(const f16x8*)(ab + (rA + mf * 16) * 128 + cb0);
      af[mf][1] = *(const f16x8*)(ab + (rA + mf * 16) * 128 + cb1);
    }
#pragma unroll
    for (int nf = 0; nf < 4; nf++) {
      bf[nf][0] = *(const f16x8*)(bb + (rB + nf * 16) * 128 + cb0);
      bf[nf][1] = *(const f16x8*)(bb + (rB + nf * 16) * 128 + cb1);
    }
    asm volatile("s_waitcnt lgkmcnt(0)" ::: "memory");
    BAR();
    if (t < 10) {
#pragma unroll
      for (int q = 0; q < 4; q++) { QST_A(c, q, t + 2); }
#pragma unroll
      for (int q = 0; q < 4; q++) { QST_B(c, q, t + 2); }
    }
    __builtin_amdgcn_s_setprio(1);
#pragma unroll
    for (int ks = 0; ks < 2; ks++)
#pragma unroll
      for (int mf = 0; mf < 4; mf++)
#pragma unroll
        for (int nf = 0; nf < 4; nf++)
          acc[mf][nf] = mm(af[mf][ks], bf[nf][ks], acc[mf][nf]);
    __builtin_amdgcn_s_setprio(0);
    if (t < 10) asm volatile("s_waitcnt vmcnt(8)" ::: "memory");
    else        asm volatile("s_waitcnt vmcnt(0)" ::: "memory");
    BAR();
  }

#pragma unroll
  for (int ni = 0; ni < 4; ni++) {
    int col = bn * 128 + wc * 64 + ni * 16 + l16;
    float bb = bias[col];
#pragma unroll
    for (int mi = 0; mi < 4; mi++) {
#pragma unroll
      for (int r = 0; r < 4; r++) {
        int row = bm * 128 + wr * 64 + mi * 16 + lq * 4 + r;
        __builtin_nontemporal_store(acc[mi][ni][r] + bb,
                                    &Cout[(size_t)row * 768 + col]);
      }
    }
  }
}

// ---------------- spatial attention: per (g,h,c); xs OUT = [n][h][c][d] -----
__global__ __launch_bounds__(512) void attn_spat_kernel(f16* __restrict__ area,
                                                        long long cstr_) {
  size_t cstr = (size_t)cstr_;
  int blk = blockIdx.x;
  int g = blk / 192, rem = blk % 192;
  int h = rem >> 4, c = rem & 15;
  size_t goff = (size_t)g * S3;
  const f16* qs = area + 3 * cstr + goff + (size_t)((h * 16 + c) * 256) * 64;
  const f16* ks = area + 4 * cstr + goff + (size_t)((h * 16 + c) * 256) * 64;
  const f16* vsb = area + 5 * cstr + goff + (size_t)(h * 16 + c) * 16384; // [nb8][d][nl8]
  f16* xsn = area + 6 * cstr + goff;   // [n][h][c][d]

  int tid = threadIdx.x;
  int wave = tid >> 6, lane = tid & 63;
  int l16 = lane & 15, lq = lane >> 4;
  __shared__ f16 plds[8][32][40];
  __shared__ f16 osm[16384];

  f32x4 zz = {0.f, 0.f, 0.f, 0.f};
  f16x8 aq[2][2];
#pragma unroll
  for (int m = 0; m < 2; m++)
#pragma unroll
    for (int kd = 0; kd < 2; kd++)
      aq[m][kd] = *(const f16x8*)&qs[(size_t)(wave * 32 + m * 16 + l16) * 64 + kd * 32 + lq * 8];

  f32x4 o[2][4];
  float mrow[2][4], lrow[2][4];
#pragma unroll
  for (int m = 0; m < 2; m++) {
#pragma unroll
    for (int n = 0; n < 4; n++) o[m][n] = zz;
#pragma unroll
    for (int r = 0; r < 4; r++) { mrow[m][r] = -1e30f; lrow[m][r] = 0.f; }
  }

  for (int kc = 0; kc < 8; kc++) {
    int k0 = kc * 32;
    f16x8 bk00 = *(const f16x8*)&ks[(size_t)(k0 + l16) * 64 + lq * 8];
    f16x8 bk01 = *(const f16x8*)&ks[(size_t)(k0 + l16) * 64 + 32 + lq * 8];
    f16x8 bk10 = *(const f16x8*)&ks[(size_t)(k0 + 16 + l16) * 64 + lq * 8];
    f16x8 bk11 = *(const f16x8*)&ks[(size_t)(k0 + 16 + l16) * 64 + 32 + lq * 8];
    f32x4 st[2][2];
#pragma unroll
    for (int m = 0; m < 2; m++) {
      st[m][0] = mm(aq[m][1], bk01, mm(aq[m][0], bk00, zz));
      st[m][1] = mm(aq[m][1], bk11, mm(aq[m][0], bk10, zz));
    }
#pragma unroll
    for (int m = 0; m < 2; m++) {
#pragma unroll
      for (int r = 0; r < 4; r++) {
        float s0 = st[m][0][r] * 0.125f, s1 = st[m][1][r] * 0.125f;
        float t = fmaxf(s0, s1);
        t = fmaxf(t, __shfl_xor(t, 1));
        t = fmaxf(t, __shfl_xor(t, 2));
        t = fmaxf(t, __shfl_xor(t, 4));
        t = fmaxf(t, __shfl_xor(t, 8));
        float mold = mrow[m][r];
        float mnew = fmaxf(mold, t);
        float fac  = __expf(mold - mnew);
        mrow[m][r] = mnew;
        float p0 = __expf(s0 - mnew), p1 = __expf(s1 - mnew);
        lrow[m][r] = lrow[m][r] * fac + p0 + p1;
        o[m][0][r] *= fac; o[m][1][r] *= fac; o[m][2][r] *= fac; o[m][3][r] *= fac;
        int prow = m * 16 + lq * 4 + r;
        plds[wave][prow][l16]      = (f16)p0;
        plds[wave][prow][16 + l16] = (f16)p1;
      }
    }
    f16x8 ap0 = *(const f16x8*)&plds[wave][l16][lq * 8];
    f16x8 ap1 = *(const f16x8*)&plds[wave][16 + l16][lq * 8];
#pragma unroll
    for (int n = 0; n < 4; n++) {
      f16x8 bv = *(const f16x8*)&vsb[((k0 >> 3) + lq) * 512 + (n * 16 + l16) * 8];
      o[0][n] = mm(ap0, bv, o[0][n]);
      o[1][n] = mm(ap1, bv, o[1][n]);
    }
  }
#pragma unroll
  for (int m = 0; m < 2; m++)
#pragma unroll
    for (int r = 0; r < 4; r++) {
      float l = lrow[m][r];
      l += __shfl_xor(l, 1);
      l += __shfl_xor(l, 2);
      l += __shfl_xor(l, 4);
      l += __shfl_xor(l, 8);
      lrow[m][r] = 1.0f / l;
    }
#pragma unroll
  for (int m = 0; m < 2; m++)
#pragma unroll
    for (int n = 0; n < 4; n++)
#pragma unroll
      for (int r = 0; r < 4; r++) {
        int row = wave * 32 + m * 16 + lq * 4 + r;
        osm[oesw(row, n * 16 + l16)] = (f16)(o[m][n][r] * lrow[m][r]);
      }
  __syncthreads();
  size_t hc64 = (size_t)(h * 16 + c) * 64;
#pragma unroll
  for (int i = 0; i < 4; i++) {
    int row = i * 64 + (tid >> 3);
    int dp  = (tid & 7) * 8;
    f16x8 v = *(const f16x8*)&osm[oesw(row, dp)];
    __builtin_nontemporal_store(v, (f16x8*)&xsn[(size_t)row * 12288 + hc64 + dp]);
  }
}

// ---------------- channel attention + combine: per (g,n), 12 heads ----------
__global__ __launch_bounds__(256) void attn_chan_kernel(f16* __restrict__ area,
                                                        long long cstr_) {
  size_t cstr = (size_t)cstr_;
  int blk = blockIdx.x;
  int g = blk >> 8, n = blk & 255;
  size_t goff = (size_t)g * S3;
  int tid = threadIdx.x;
  int wave = tid >> 6, lane = tid & 63;
  int l16 = lane & 15, lq = lane >> 4;
  __shared__ f16 xsl[12288];
  __shared__ f16 prl[12288];
  __shared__ f16 plds[4][16][40];

  const f16* xsn = area + 6 * cstr + goff + (size_t)n * 12288;
#pragma unroll
  for (int i = 0; i < 6; i++) {
    int seg = wave * 6 + i;
    __builtin_amdgcn_global_load_lds(
        (const __attribute__((address_space(1))) void*)(xsn + seg * 512 + lane * 8),
        (__attribute__((address_space(3))) void*)((char*)xsl + seg * 1024), 16, 0, 0);
  }
  if (lane < 16) {
#pragma unroll
    for (int j = 0; j < 16; j++) plds[wave][lane][16 + j] = (f16)0.f;
  }
  asm volatile("s_waitcnt vmcnt(0)" ::: "memory");
  __syncthreads();

  f32x4 zz = {0.f, 0.f, 0.f, 0.f};
  for (int hi = 0; hi < 3; hi++) {
    int h = wave + hi * 4;
    const f16* q = area + 0 * cstr + goff + (size_t)((h * 256 + n) * 16) * 64;
    const f16* k = area + 1 * cstr + goff + (size_t)((h * 256 + n) * 16) * 64;
    const f16* v = area + 2 * cstr + goff + (size_t)((h * 256 + n) * 64) * 16; // [d][c]
    f16x8 a0 = *(const f16x8*)&q[l16 * 64 + lq * 8];
    f16x8 a1 = *(const f16x8*)&q[l16 * 64 + 32 + lq * 8];
    f16x8 b0 = *(const f16x8*)&k[l16 * 64 + lq * 8];
    f16x8 b1 = *(const f16x8*)&k[l16 * 64 + 32 + lq * 8];
    f32x4 s = mm(a1, b1, mm(a0, b0, zz));
    float p[4];
#pragma unroll
    for (int r = 0; r < 4; r++) {
      float t = s[r] * 0.125f;
      float mx = t;
      mx = fmaxf(mx, __shfl_xor(mx, 1));
      mx = fmaxf(mx, __shfl_xor(mx, 2));
      mx = fmaxf(mx, __shfl_xor(mx, 4));
      mx = fmaxf(mx, __shfl_xor(mx, 8));
      float e = __expf(t - mx);
      float sum = e;
      sum += __shfl_xor(sum, 1);
      sum += __shfl_xor(sum, 2);
      sum += __shfl_xor(sum, 4);
      sum += __shfl_xor(sum, 8);
      p[r] = e / sum;
    }
#pragma unroll
    for (int r = 0; r < 4; r++)
      plds[wave][lq * 4 + r][l16] = (f16)p[r];
    f16x8 ap = *(const f16x8*)&plds[wave][l16][lq * 8];
#pragma unroll
    for (int nt = 0; nt < 4; nt++) {
      f16x8 bv = *(const f16x8*)&v[(nt * 16 + l16) * 16 + lq * 8];
      f32x4 o = mm(ap, bv, zz);
#pragma unroll
      for (int r = 0; r < 4; r++) {
        int cq = lq * 4 + r, d = nt * 16 + l16;
        int idx = h * 1024 + cq * 64 + d;
        float xsv = (float)xsl[idx];
        prl[idx] = (f16)(o[r] * xsv);
      }
    }
  }
  __syncthreads();
  f16* prod = area + 3 * cstr + goff + (size_t)n * 12288;
#pragma unroll
  for (int i = 0; i < 6; i++) {
    f16x8 v = *(const f16x8*)&prl[i * 2048 + tid * 8];
    __builtin_nontemporal_store(v, (f16x8*)&prod[i * 2048 + tid * 8]);
  }
}

// ---------------- host ------------------------------------------------------
extern "C" void kernel_launch(void* const* d_in, const int* in_sizes, int n_in,
                              void* d_out, int out_size, void* d_ws, size_t ws_size,
                              hipStream_t stream) {
  const float* x      = (const float*)d_in[0];
  const float* w_qkv  = (const float*)d_in[1];
  const float* w_proj = (const float*)d_in[2];
  const float* b_proj = (const float*)d_in[3];
  float* out = (float*)d_out;
  f16* ws = (f16*)d_ws;

  const size_t W16T = 4608ull * 768;
  const size_t WPT  = 768ull * 768;
  f16* w16t = ws;
  f16* wpt  = ws + W16T;
  f16* area = wpt + WPT;

  // 7-component plan: 0 qc, 1 kc, 2 vc, 3 qs->prod, 4 ks, 5 vs, 6 x16->xs
  int G = 8;
  while (G > 1 && (W16T + WPT + 7ull * G * S3) * 2 > ws_size) G >>= 1;
  int nch = 8 / G;
  long long cstr = (long long)G * S3;
  f16* x16 = area + 6 * (size_t)cstr;

  cvt_T_kernel<<<dim3(144, 24), 256, 0, stream>>>(w_qkv, w16t, 768, 4608);
  cvt_T_kernel<<<dim3(24, 24), 256, 0, stream>>>(w_proj, wpt, 768, 768);

  for (int ch = 0; ch < nch; ch++) {
    size_t b0 = (size_t)ch * G;
    cvt_x_kernel<<<G * 1536, 256, 0, stream>>>(x + b0 * S3, x16);
    gemm_qkv8p<<<G * 288, 512, 0, stream>>>(x16, w16t, area, cstr);
    attn_spat_kernel<<<G * 192, 512, 0, stream>>>(area, cstr);
    attn_chan_kernel<<<G * 256, 256, 0, stream>>>(area, cstr);
    gemm_projT<<<G * 192, 256, 0, stream>>>(area + 3 * (size_t)cstr, wpt, b_proj,
                                            out + b0 * S3);
  }
}

// Round 15
// 498.519 us; speedup vs baseline: 1.1877x; 1.0112x over previous
//
#include <hip/hip_runtime.h>

typedef _Float16 f16;
typedef f16  f16x8 __attribute__((ext_vector_type(8)));
typedef float f32x4 __attribute__((ext_vector_type(4)));

#define S3 3145728LL   // per-batch per-component elems (12*256*16*64 = 4096*768)

__device__ __forceinline__ f32x4 mm(f16x8 a, f16x8 b, f32x4 c) {
  return __builtin_amdgcn_mfma_f32_16x16x32_f16(a, b, c, 0, 0, 0);
}
__device__ __forceinline__ void BAR() { asm volatile("s_barrier" ::: "memory"); }

// epilogue LDS swizzle for [128][128] f16 tile
__device__ __forceinline__ int esw(int t, int col) {
  return t * 128 + ((((col >> 3) ^ ((t ^ (t >> 3)) & 7)) << 3) | (col & 7));
}
// swizzle for [256][64] f16 tile (attn_spat O staging)
__device__ __forceinline__ int oesw(int t, int col) {
  return t * 64 + ((((col >> 3) ^ (t & 7)) << 3) | (col & 7));
}

// ---------------- transpose + fp32->fp16 convert: out[Cc][R] = in[R][Cc] ----
__global__ void cvt_T_kernel(const float* __restrict__ in, f16* __restrict__ out,
                             int R, int Cc) {
  __shared__ float tile[32][33];
  int tc = blockIdx.x, tr = blockIdx.y;
  int lr = threadIdx.x & 31, lw = threadIdx.x >> 5;
  int c0 = tc * 32, r0 = tr * 32;
#pragma unroll
  for (int i = 0; i < 4; i++)
    tile[lw + 8 * i][lr] = in[(size_t)(r0 + lw + 8 * i) * Cc + c0 + lr];
  __syncthreads();
#pragma unroll
  for (int i = 0; i < 4; i++)
    out[(size_t)(c0 + lw + 8 * i) * R + r0 + lr] = (f16)tile[lr][lw + 8 * i];
}

// ---------------- x fp32 -> f16 (NT reads: x is never re-read) -------------
__global__ void cvt_x_kernel(const float* __restrict__ in, f16* __restrict__ out) {
  size_t i = ((size_t)blockIdx.x * 256 + threadIdx.x) * 8;
  f32x4 a = __builtin_nontemporal_load((const f32x4*)(in + i));
  f32x4 b = __builtin_nontemporal_load((const f32x4*)(in + i + 4));
  f16x8 o;
#pragma unroll
  for (int j = 0; j < 4; j++) { o[j] = (f16)a[j]; o[4 + j] = (f16)b[j]; }
  *(f16x8*)(out + i) = o;
}

// =================== QKV GEMM: 128x128 tile, BK=64, 64KB LDS ================
#define QST_A(c, q, kt) __builtin_amdgcn_global_load_lds( \
    (const __attribute__((address_space(1))) void*)(aSrc + (size_t)(q) * 24576 + (size_t)(kt) * 64), \
    (__attribute__((address_space(3))) void*)((char*)lds + (c) * 32768 + (q) * 1024 * 4 + wave * 1024), 16, 0, 0)
#define QST_B(c, q, kt) __builtin_amdgcn_global_load_lds( \
    (const __attribute__((address_space(1))) void*)(bSrc + (size_t)(q) * 24576 + (size_t)(kt) * 64), \
    (__attribute__((address_space(3))) void*)((char*)lds + 16384 + (c) * 32768 + (q) * 1024 * 4 + wave * 1024), 16, 0, 0)

__global__ __launch_bounds__(256, 2) void gemm_qkvT(
    const f16* __restrict__ A, const f16* __restrict__ Bt,
    f16* __restrict__ area, long long cstr_) {
  __shared__ f16 lds[32768];   // 64KB: 2 x (A 16KB | B 16KB); epilogue reuses 32KB
  size_t cstr = (size_t)cstr_;
  int id  = blockIdx.x;
  int cpx = gridDim.x >> 3;
  int id2 = (id & 7) * cpx + (id >> 3);       // XCD swizzle (grid % 8 == 0)
  int sr = id2 / 288, rr = id2 % 288;
  int bm = sr * 8 + (rr & 7), bn = rr >> 3;   // bm 0..G*32-1, bn 0..35

  int tid = threadIdx.x;
  int wave = tid >> 6, lane = tid & 63;
  int l16 = lane & 15, lq = lane >> 4;
  int wr = wave >> 1, wc = wave & 1;          // 2 x 2 wave grid
  int l7 = l16 & 7;
  int cb0 = ((lq) ^ l7) << 4;
  int cb1 = ((4 + lq) ^ l7) << 4;

  const f16* aSrc = A  + (size_t)(bm * 128 + (tid >> 3)) * 768 +
                    (((tid & 7) ^ ((tid >> 3) & 7)) << 3);
  const f16* bSrc = Bt + (size_t)(bn * 128 + (tid >> 3)) * 768 +
                    (((tid & 7) ^ ((tid >> 3) & 7)) << 3);

  f32x4 zz = {0.f, 0.f, 0.f, 0.f};
  f32x4 acc[4][4];
#pragma unroll
  for (int m = 0; m < 4; m++)
#pragma unroll
    for (int n = 0; n < 4; n++) acc[m][n] = zz;

#pragma unroll
  for (int q = 0; q < 4; q++) { QST_A(0, q, 0); }
#pragma unroll
  for (int q = 0; q < 4; q++) { QST_B(0, q, 0); }
#pragma unroll
  for (int q = 0; q < 4; q++) { QST_A(1, q, 1); }
#pragma unroll
  for (int q = 0; q < 4; q++) { QST_B(1, q, 1); }
  asm volatile("s_waitcnt vmcnt(8)" ::: "memory");
  BAR();

  f16x8 af[4][2], bf[4][2];
#pragma unroll 2
  for (int t = 0; t < 12; ++t) {
    int c = t & 1;
    const char* ab = (const char*)lds + c * 32768;
    const char* bb = ab + 16384;
    int rA = wr * 64 + l16;
    int rB = wc * 64 + l16;
#pragma unroll
    for (int mf = 0; mf < 4; mf++) {
      af[mf][0] = *(const f16x8*)(ab + (rA + mf * 16) * 128 + cb0);
      af[mf][1] = *(const f16x8*)(ab + (rA + mf * 16) * 128 + cb1);
    }
#pragma unroll
    for (int nf = 0; nf < 4; nf++) {
      bf[nf][0] = *(const f16x8*)(bb + (rB + nf * 16) * 128 + cb0);
      bf[nf][1] = *(const f16x8*)(bb + (rB + nf * 16) * 128 + cb1);
    }
    asm volatile("s_waitcnt lgkmcnt(0)" ::: "memory");
    BAR();
    if (t < 10) {
#pragma unroll
      for (int q = 0; q < 4; q++) { QST_A(c, q, t + 2); }
#pragma unroll
      for (int q = 0; q < 4; q++) { QST_B(c, q, t + 2); }
    }
    __builtin_amdgcn_s_setprio(1);
#pragma unroll
    for (int ks = 0; ks < 2; ks++)
#pragma unroll
      for (int mf = 0; mf < 4; mf++)
#pragma unroll
        for (int nf = 0; nf < 4; nf++)
          acc[mf][nf] = mm(af[mf][ks], bf[nf][ks], acc[mf][nf]);
    __builtin_amdgcn_s_setprio(0);
    if (t < 10) asm volatile("s_waitcnt vmcnt(8)" ::: "memory");
    else        asm volatile("s_waitcnt vmcnt(0)" ::: "memory");
    BAR();
  }

  // ---- coalesced LDS epilogue (32KB [128][128] C-tile) ----
  int s  = bn / 6;
  int h0 = (bn % 6) * 2;
  size_t comp;
  if (s == 0) comp = 0; else if (s == 1) comp = 1; else if (s == 2) comp = 3;
  else if (s == 3) comp = 4; else if (s == 4) comp = 2; else comp = 5;
  int g = (bm * 128) >> 12;
  size_t base = comp * cstr + (size_t)g * S3;
  int n0 = (bm & 31) * 8;

  __syncthreads();
#pragma unroll
  for (int mi = 0; mi < 4; mi++)
#pragma unroll
    for (int ni = 0; ni < 4; ni++)
#pragma unroll
      for (int r = 0; r < 4; r++) {
        int t = wr * 64 + mi * 16 + lq * 4 + r;
        int col = wc * 64 + ni * 16 + l16;
        lds[esw(t, col)] = (f16)acc[mi][ni][r];
      }
  __syncthreads();

  if (s < 2) {            // qc/kc [h][n][c][d]
#pragma unroll
    for (int i = 0; i < 4; i++) {
      int u = wave * 4 + i;
      int hl = u >> 3, j16 = u & 7;
#pragma unroll
      for (int half = 0; half < 2; half++) {
        int e0 = half * 512 + lane * 8;
        int cc = e0 >> 6, d0 = e0 & 63;
        f16x8 v = *(const f16x8*)&lds[esw(j16 * 16 + cc, hl * 64 + d0)];
        __builtin_nontemporal_store(v, (f16x8*)&area[base +
            (size_t)(h0 + hl) * 262144 + (size_t)(n0 + j16) * 1024 + e0]);
      }
    }
  } else if (s < 4) {     // qs/ks [h][c][n][d]
#pragma unroll
    for (int i = 0; i < 8; i++) {
      int u = wave * 8 + i;
      int hl = u >> 4, cc = u & 15;
      int e = lane * 8;
      int nl = e >> 6, d0 = e & 63;
      f16x8 v = *(const f16x8*)&lds[esw(nl * 16 + cc, hl * 64 + d0)];
      __builtin_nontemporal_store(v, (f16x8*)&area[base +
          (size_t)((h0 + hl) * 16 + cc) * 16384 + (size_t)n0 * 64 + e]);
    }
  } else if (s == 4) {    // vc [h][n][d][c]
#pragma unroll
    for (int i = 0; i < 4; i++) {
      int u = wave * 4 + i;
      int hl = u >> 3, j8 = u & 7;
#pragma unroll
      for (int half = 0; half < 2; half++) {
        int e0 = half * 512 + lane * 8;
        int d0 = e0 >> 4, cb = e0 & 15;
        f16x8 v;
#pragma unroll
        for (int j = 0; j < 8; j++)
          v[j] = lds[esw(j8 * 16 + cb + j, hl * 64 + d0)];
        __builtin_nontemporal_store(v, (f16x8*)&area[base +
            (size_t)((h0 + hl) * 256 + n0 + j8) * 1024 + e0]);
      }
    }
  } else {                // vs blocked [h][c][nb8][d][nl8]
#pragma unroll
    for (int i = 0; i < 8; i++) {
      int u = wave * 8 + i;
      int hl = u >> 4, cc = u & 15;
      int e = lane * 8;
      int d0 = e >> 3;
      f16x8 v;
#pragma unroll
      for (int j = 0; j < 8; j++)
        v[j] = lds[esw(j * 16 + cc, hl * 64 + d0)];
      __builtin_nontemporal_store(v, (f16x8*)&area[base +
          ((size_t)((h0 + hl) * 16 + cc) * 32 + (bm & 31)) * 512 + e]);
    }
  }
}

// ---------- proj GEMM: 128x128 tile, same pipeline, out = A*wpt^T + bias ----
__global__ __launch_bounds__(256, 2) void gemm_projT(
    const f16* __restrict__ A,       // prod [G*4096][768] (comp3)
    const f16* __restrict__ Bt,      // wpt [768][768]
    const float* __restrict__ bias, float* __restrict__ Cout) {
  __shared__ f16 lds[32768];
  int id  = blockIdx.x;
  int cpx = gridDim.x >> 3;
  int id2 = (id & 7) * cpx + (id >> 3);       // grid = G*192, %8==0
  int sr = id2 / 48, rr = id2 % 48;
  int bm = sr * 8 + (rr & 7), bn = rr >> 3;   // bm 0..G*32-1, bn 0..5

  int tid = threadIdx.x;
  int wave = tid >> 6, lane = tid & 63;
  int l16 = lane & 15, lq = lane >> 4;
  int wr = wave >> 1, wc = wave & 1;
  int l7 = l16 & 7;
  int cb0 = ((lq) ^ l7) << 4;
  int cb1 = ((4 + lq) ^ l7) << 4;

  const f16* aSrc = A  + (size_t)(bm * 128 + (tid >> 3)) * 768 +
                    (((tid & 7) ^ ((tid >> 3) & 7)) << 3);
  const f16* bSrc = Bt + (size_t)(bn * 128 + (tid >> 3)) * 768 +
                    (((tid & 7) ^ ((tid >> 3) & 7)) << 3);

  f32x4 zz = {0.f, 0.f, 0.f, 0.f};
  f32x4 acc[4][4];
#pragma unroll
  for (int m = 0; m < 4; m++)
#pragma unroll
    for (int n = 0; n < 4; n++) acc[m][n] = zz;

#pragma unroll
  for (int q = 0; q < 4; q++) { QST_A(0, q, 0); }
#pragma unroll
  for (int q = 0; q < 4; q++) { QST_B(0, q, 0); }
#pragma unroll
  for (int q = 0; q < 4; q++) { QST_A(1, q, 1); }
#pragma unroll
  for (int q = 0; q < 4; q++) { QST_B(1, q, 1); }
  asm volatile("s_waitcnt vmcnt(8)" ::: "memory");
  BAR();

  f16x8 af[4][2], bf[4][2];
#pragma unroll 2
  for (int t = 0; t < 12; ++t) {
    int c = t & 1;
    const char* ab = (const char*)lds + c * 32768;
    const char* bb = ab + 16384;
    int rA = wr * 64 + l16;
    int rB = wc * 64 + l16;
#pragma unroll
    for (int mf = 0; mf < 4; mf++) {
      af[mf][0] = *(const f16x8*)(ab + (rA + mf * 16) * 128 + cb0);
      af[mf][1] = *(const f16x8*)(ab + (rA + mf * 16) * 128 + cb1);
    }
#pragma unroll
    for (int nf = 0; nf < 4; nf++) {
      bf[nf][0] = *(const f16x8*)(bb + (rB + nf * 16) * 128 + cb0);
      bf[nf][1] = *(const f16x8*)(bb + (rB + nf * 16) * 128 + cb1);
    }
    asm volatile("s_waitcnt lgkmcnt(0)" ::: "memory");
    BAR();
    if (t < 10) {
#pragma unroll
      for (int q = 0; q < 4; q++) { QST_A(c, q, t + 2); }
#pragma unroll
      for (int q = 0; q < 4; q++) { QST_B(c, q, t + 2); }
    }
    __builtin_amdgcn_s_setprio(1);
#pragma unroll
    for (int ks = 0; ks < 2; ks++)
#pragma unroll
      for (int mf = 0; mf < 4; mf++)
#pragma unroll
        for (int nf = 0; nf < 4; nf++)
          acc[mf][nf] = mm(af[mf][ks], bf[nf][ks], acc[mf][nf]);
    __builtin_amdgcn_s_setprio(0);
    if (t < 10) asm volatile("s_waitcnt vmcnt(8)" ::: "memory");
    else        asm volatile("s_waitcnt vmcnt(0)" ::: "memory");
    BAR();
  }

  // direct fp32 epilogue with bias
#pragma unroll
  for (int ni = 0; ni < 4; ni++) {
    int col = bn * 128 + wc * 64 + ni * 16 + l16;
    float bb = bias[col];
#pragma unroll
    for (int mi = 0; mi < 4; mi++) {
#pragma unroll
      for (int r = 0; r < 4; r++) {
        int row = bm * 128 + wr * 64 + mi * 16 + lq * 4 + r;
        __builtin_nontemporal_store(acc[mi][ni][r] + bb,
                                    &Cout[(size_t)row * 768 + col]);
      }
    }
  }
}

// ---------------- spatial attention: per (g,h,c); xs OUT = [n][h][c][d] -----
// T13 defer-max: skip O-rescale when row-max growth <= 8 (P bounded by e^8).
__global__ __launch_bounds__(512) void attn_spat_kernel(f16* __restrict__ area,
                                                        long long cstr_) {
  size_t cstr = (size_t)cstr_;
  int blk = blockIdx.x;
  int g = blk / 192, rem = blk % 192;
  int h = rem >> 4, c = rem & 15;
  size_t goff = (size_t)g * S3;
  const f16* qs = area + 3 * cstr + goff + (size_t)((h * 16 + c) * 256) * 64;
  const f16* ks = area + 4 * cstr + goff + (size_t)((h * 16 + c) * 256) * 64;
  const f16* vsb = area + 5 * cstr + goff + (size_t)(h * 16 + c) * 16384; // [nb8][d][nl8]
  f16* xsn = area + 6 * cstr + goff;   // [n][h][c][d]

  int tid = threadIdx.x;
  int wave = tid >> 6, lane = tid & 63;
  int l16 = lane & 15, lq = lane >> 4;
  __shared__ f16 plds[8][32][40];
  __shared__ f16 osm[16384];          // [256][64] swizzled (oesw)

  f32x4 zz = {0.f, 0.f, 0.f, 0.f};
  f16x8 aq[2][2];
#pragma unroll
  for (int m = 0; m < 2; m++)
#pragma unroll
    for (int kd = 0; kd < 2; kd++)
      aq[m][kd] = *(const f16x8*)&qs[(size_t)(wave * 32 + m * 16 + l16) * 64 + kd * 32 + lq * 8];

  f32x4 o[2][4];
  float mrow[2][4], lrow[2][4];
#pragma unroll
  for (int m = 0; m < 2; m++) {
#pragma unroll
    for (int n = 0; n < 4; n++) o[m][n] = zz;
#pragma unroll
    for (int r = 0; r < 4; r++) { mrow[m][r] = -1e30f; lrow[m][r] = 0.f; }
  }

  for (int kc = 0; kc < 8; kc++) {
    int k0 = kc * 32;
    f16x8 bk00 = *(const f16x8*)&ks[(size_t)(k0 + l16) * 64 + lq * 8];
    f16x8 bk01 = *(const f16x8*)&ks[(size_t)(k0 + l16) * 64 + 32 + lq * 8];
    f16x8 bk10 = *(const f16x8*)&ks[(size_t)(k0 + 16 + l16) * 64 + lq * 8];
    f16x8 bk11 = *(const f16x8*)&ks[(size_t)(k0 + 16 + l16) * 64 + 32 + lq * 8];
    f32x4 st[2][2];
#pragma unroll
    for (int m = 0; m < 2; m++) {
      st[m][0] = mm(aq[m][1], bk01, mm(aq[m][0], bk00, zz));
      st[m][1] = mm(aq[m][1], bk11, mm(aq[m][0], bk10, zz));
    }
#pragma unroll
    for (int m = 0; m < 2; m++) {
#pragma unroll
      for (int r = 0; r < 4; r++) {
        float s0 = st[m][0][r] * 0.125f, s1 = st[m][1][r] * 0.125f;
        float t = fmaxf(s0, s1);
        t = fmaxf(t, __shfl_xor(t, 1));
        t = fmaxf(t, __shfl_xor(t, 2));
        t = fmaxf(t, __shfl_xor(t, 4));
        t = fmaxf(t, __shfl_xor(t, 8));
        float mold = mrow[m][r];
        if (!__all(t - mold <= 8.f)) {   // defer-max: rescale only on real growth
          float mnew = fmaxf(mold, t);
          float fac  = __expf(mold - mnew);
          mrow[m][r] = mnew;
          lrow[m][r] *= fac;
          o[m][0][r] *= fac; o[m][1][r] *= fac; o[m][2][r] *= fac; o[m][3][r] *= fac;
          mold = mnew;
        }
        float p0 = __expf(s0 - mold), p1 = __expf(s1 - mold);
        lrow[m][r] += p0 + p1;
        int prow = m * 16 + lq * 4 + r;
        plds[wave][prow][l16]      = (f16)p0;
        plds[wave][prow][16 + l16] = (f16)p1;
      }
    }
    f16x8 ap0 = *(const f16x8*)&plds[wave][l16][lq * 8];
    f16x8 ap1 = *(const f16x8*)&plds[wave][16 + l16][lq * 8];
#pragma unroll
    for (int n = 0; n < 4; n++) {
      f16x8 bv = *(const f16x8*)&vsb[((k0 >> 3) + lq) * 512 + (n * 16 + l16) * 8];
      o[0][n] = mm(ap0, bv, o[0][n]);
      o[1][n] = mm(ap1, bv, o[1][n]);
    }
  }
#pragma unroll
  for (int m = 0; m < 2; m++)
#pragma unroll
    for (int r = 0; r < 4; r++) {
      float l = lrow[m][r];
      l += __shfl_xor(l, 1);
      l += __shfl_xor(l, 2);
      l += __shfl_xor(l, 4);
      l += __shfl_xor(l, 8);
      lrow[m][r] = 1.0f / l;
    }
#pragma unroll
  for (int m = 0; m < 2; m++)
#pragma unroll
    for (int n = 0; n < 4; n++)
#pragma unroll
      for (int r = 0; r < 4; r++) {
        int row = wave * 32 + m * 16 + lq * 4 + r;
        osm[oesw(row, n * 16 + l16)] = (f16)(o[m][n][r] * lrow[m][r]);
      }
  __syncthreads();
  size_t hc64 = (size_t)(h * 16 + c) * 64;
#pragma unroll
  for (int i = 0; i < 4; i++) {
    int row = i * 64 + (tid >> 3);
    int dp  = (tid & 7) * 8;
    f16x8 v = *(const f16x8*)&osm[oesw(row, dp)];
    __builtin_nontemporal_store(v, (f16x8*)&xsn[(size_t)row * 12288 + hc64 + dp]);
  }
}

// ---------------- channel attention + combine: per (g,n), 12 heads ----------
// xs IN = [n][h][c][d] (comp6); prod OUT = [n][h][c][d] (comp3, qs dead).
__global__ __launch_bounds__(256) void attn_chan_kernel(f16* __restrict__ area,
                                                        long long cstr_) {
  size_t cstr = (size_t)cstr_;
  int blk = blockIdx.x;
  int g = blk >> 8, n = blk & 255;
  size_t goff = (size_t)g * S3;
  int tid = threadIdx.x;
  int wave = tid >> 6, lane = tid & 63;
  int l16 = lane & 15, lq = lane >> 4;
  __shared__ f16 xsl[12288];
  __shared__ f16 prl[12288];
  __shared__ f16 plds[4][16][40];

  const f16* xsn = area + 6 * cstr + goff + (size_t)n * 12288;
#pragma unroll
  for (int i = 0; i < 6; i++) {
    int seg = wave * 6 + i;
    __builtin_amdgcn_global_load_lds(
        (const __attribute__((address_space(1))) void*)(xsn + seg * 512 + lane * 8),
        (__attribute__((address_space(3))) void*)((char*)xsl + seg * 1024), 16, 0, 0);
  }
  if (lane < 16) {
#pragma unroll
    for (int j = 0; j < 16; j++) plds[wave][lane][16 + j] = (f16)0.f;
  }
  asm volatile("s_waitcnt vmcnt(0)" ::: "memory");
  __syncthreads();

  f32x4 zz = {0.f, 0.f, 0.f, 0.f};
  for (int hi = 0; hi < 3; hi++) {
    int h = wave + hi * 4;
    const f16* q = area + 0 * cstr + goff + (size_t)((h * 256 + n) * 16) * 64;
    const f16* k = area + 1 * cstr + goff + (size_t)((h * 256 + n) * 16) * 64;
    const f16* v = area + 2 * cstr + goff + (size_t)((h * 256 + n) * 64) * 16; // [d][c]
    f16x8 a0 = *(const f16x8*)&q[l16 * 64 + lq * 8];
    f16x8 a1 = *(const f16x8*)&q[l16 * 64 + 32 + lq * 8];
    f16x8 b0 = *(const f16x8*)&k[l16 * 64 + lq * 8];
    f16x8 b1 = *(const f16x8*)&k[l16 * 64 + 32 + lq * 8];
    f32x4 s = mm(a1, b1, mm(a0, b0, zz));
    float p[4];
#pragma unroll
    for (int r = 0; r < 4; r++) {
      float t = s[r] * 0.125f;
      float mx = t;
      mx = fmaxf(mx, __shfl_xor(mx, 1));
      mx = fmaxf(mx, __shfl_xor(mx, 2));
      mx = fmaxf(mx, __shfl_xor(mx, 4));
      mx = fmaxf(mx, __shfl_xor(mx, 8));
      float e = __expf(t - mx);
      float sum = e;
      sum += __shfl_xor(sum, 1);
      sum += __shfl_xor(sum, 2);
      sum += __shfl_xor(sum, 4);
      sum += __shfl_xor(sum, 8);
      p[r] = e / sum;
    }
#pragma unroll
    for (int r = 0; r < 4; r++)
      plds[wave][lq * 4 + r][l16] = (f16)p[r];
    f16x8 ap = *(const f16x8*)&plds[wave][l16][lq * 8];
#pragma unroll
    for (int nt = 0; nt < 4; nt++) {
      f16x8 bv = *(const f16x8*)&v[(nt * 16 + l16) * 16 + lq * 8];
      f32x4 o = mm(ap, bv, zz);
#pragma unroll
      for (int r = 0; r < 4; r++) {
        int cq = lq * 4 + r, d = nt * 16 + l16;
        int idx = h * 1024 + cq * 64 + d;
        float xsv = (float)xsl[idx];
        prl[idx] = (f16)(o[r] * xsv);
      }
    }
  }
  __syncthreads();
  f16* prod = area + 3 * cstr + goff + (size_t)n * 12288;
#pragma unroll
  for (int i = 0; i < 6; i++) {
    f16x8 v = *(const f16x8*)&prl[i * 2048 + tid * 8];
    __builtin_nontemporal_store(v, (f16x8*)&prod[i * 2048 + tid * 8]);
  }
}

// ---------------- host ------------------------------------------------------
extern "C" void kernel_launch(void* const* d_in, const int* in_sizes, int n_in,
                              void* d_out, int out_size, void* d_ws, size_t ws_size,
                              hipStream_t stream) {
  const float* x      = (const float*)d_in[0];
  const float* w_qkv  = (const float*)d_in[1];
  const float* w_proj = (const float*)d_in[2];
  const float* b_proj = (const float*)d_in[3];
  float* out = (float*)d_out;
  f16* ws = (f16*)d_ws;

  const size_t W16T = 4608ull * 768;
  const size_t WPT  = 768ull * 768;
  f16* w16t = ws;
  f16* wpt  = ws + W16T;
  f16* area = wpt + WPT;

  // 7-component plan: 0 qc, 1 kc, 2 vc, 3 qs->prod, 4 ks, 5 vs, 6 x16->xs
  int G = 8;  // batches per chunk; shrink until scratch fits
  while (G > 1 && (W16T + WPT + 7ull * G * S3) * 2 > ws_size) G >>= 1;
  int nch = 8 / G;
  long long cstr = (long long)G * S3;
  f16* x16 = area + 6 * (size_t)cstr;   // aliased with xs (dead before attn_spat)

  cvt_T_kernel<<<dim3(144, 24), 256, 0, stream>>>(w_qkv, w16t, 768, 4608);
  cvt_T_kernel<<<dim3(24, 24), 256, 0, stream>>>(w_proj, wpt, 768, 768);

  for (int ch = 0; ch < nch; ch++) {
    size_t b0 = (size_t)ch * G;
    cvt_x_kernel<<<G * 1536, 256, 0, stream>>>(x + b0 * S3, x16);
    gemm_qkvT<<<G * 1152, 256, 0, stream>>>(x16, w16t, area, cstr);
    attn_spat_kernel<<<G * 192, 512, 0, stream>>>(area, cstr);
    attn_chan_kernel<<<G * 256, 256, 0, stream>>>(area, cstr);
    gemm_projT<<<G * 192, 256, 0, stream>>>(area + 3 * (size_t)cstr, wpt, b_proj,
                                            out + b0 * S3);
  }
}

// Round 16
// 482.303 us; speedup vs baseline: 1.2277x; 1.0336x over previous
//
#include <hip/hip_runtime.h>

typedef _Float16 f16;
typedef f16  f16x8 __attribute__((ext_vector_type(8)));
typedef float f32x4 __attribute__((ext_vector_type(4)));

#define S3 3145728LL   // per-batch per-component elems (12*256*16*64 = 4096*768)

__device__ __forceinline__ f32x4 mm(f16x8 a, f16x8 b, f32x4 c) {
  return __builtin_amdgcn_mfma_f32_16x16x32_f16(a, b, c, 0, 0, 0);
}
__device__ __forceinline__ void BAR() { asm volatile("s_barrier" ::: "memory"); }

// epilogue LDS swizzle for [128][128] f16 tile
__device__ __forceinline__ int esw(int t, int col) {
  return t * 128 + ((((col >> 3) ^ ((t ^ (t >> 3)) & 7)) << 3) | (col & 7));
}
// swizzle for [256][64] f16 tile (attn_spat O staging)
__device__ __forceinline__ int oesw(int t, int col) {
  return t * 64 + ((((col >> 3) ^ (t & 7)) << 3) | (col & 7));
}

// ---------------- transpose + fp32->fp16 convert: out[Cc][R] = in[R][Cc] ----
__global__ void cvt_T_kernel(const float* __restrict__ in, f16* __restrict__ out,
                             int R, int Cc) {
  __shared__ float tile[32][33];
  int tc = blockIdx.x, tr = blockIdx.y;
  int lr = threadIdx.x & 31, lw = threadIdx.x >> 5;
  int c0 = tc * 32, r0 = tr * 32;
#pragma unroll
  for (int i = 0; i < 4; i++)
    tile[lw + 8 * i][lr] = in[(size_t)(r0 + lw + 8 * i) * Cc + c0 + lr];
  __syncthreads();
#pragma unroll
  for (int i = 0; i < 4; i++)
    out[(size_t)(c0 + lw + 8 * i) * R + r0 + lr] = (f16)tile[lr][lw + 8 * i];
}

// ---------------- x fp32 -> f16 (NT reads: x is never re-read) -------------
__global__ void cvt_x_kernel(const float* __restrict__ in, f16* __restrict__ out) {
  size_t i = ((size_t)blockIdx.x * 256 + threadIdx.x) * 8;
  f32x4 a = __builtin_nontemporal_load((const f32x4*)(in + i));
  f32x4 b = __builtin_nontemporal_load((const f32x4*)(in + i + 4));
  f16x8 o;
#pragma unroll
  for (int j = 0; j < 4; j++) { o[j] = (f16)a[j]; o[4 + j] = (f16)b[j]; }
  *(f16x8*)(out + i) = o;
}

// =================== QKV GEMM: 128x128 tile, BK=64, 64KB LDS ================
#define QST_A(c, q, kt) __builtin_amdgcn_global_load_lds( \
    (const __attribute__((address_space(1))) void*)(aSrc + (size_t)(q) * 24576 + (size_t)(kt) * 64), \
    (__attribute__((address_space(3))) void*)((char*)lds + (c) * 32768 + (q) * 1024 * 4 + wave * 1024), 16, 0, 0)
#define QST_B(c, q, kt) __builtin_amdgcn_global_load_lds( \
    (const __attribute__((address_space(1))) void*)(bSrc + (size_t)(q) * 24576 + (size_t)(kt) * 64), \
    (__attribute__((address_space(3))) void*)((char*)lds + 16384 + (c) * 32768 + (q) * 1024 * 4 + wave * 1024), 16, 0, 0)

__global__ __launch_bounds__(256, 2) void gemm_qkvT(
    const f16* __restrict__ A, const f16* __restrict__ Bt,
    f16* __restrict__ area, long long cstr_) {
  __shared__ f16 lds[32768];   // 64KB: 2 x (A 16KB | B 16KB); epilogue reuses 32KB
  size_t cstr = (size_t)cstr_;
  int id  = blockIdx.x;
  int cpx = gridDim.x >> 3;
  int id2 = (id & 7) * cpx + (id >> 3);       // XCD swizzle (grid % 8 == 0)
  int sr = id2 / 288, rr = id2 % 288;
  int bm = sr * 8 + (rr & 7), bn = rr >> 3;   // bm 0..G*32-1, bn 0..35

  int tid = threadIdx.x;
  int wave = tid >> 6, lane = tid & 63;
  int l16 = lane & 15, lq = lane >> 4;
  int wr = wave >> 1, wc = wave & 1;          // 2 x 2 wave grid
  int l7 = l16 & 7;
  int cb0 = ((lq) ^ l7) << 4;
  int cb1 = ((4 + lq) ^ l7) << 4;

  const f16* aSrc = A  + (size_t)(bm * 128 + (tid >> 3)) * 768 +
                    (((tid & 7) ^ ((tid >> 3) & 7)) << 3);
  const f16* bSrc = Bt + (size_t)(bn * 128 + (tid >> 3)) * 768 +
                    (((tid & 7) ^ ((tid >> 3) & 7)) << 3);

  f32x4 zz = {0.f, 0.f, 0.f, 0.f};
  f32x4 acc[4][4];
#pragma unroll
  for (int m = 0; m < 4; m++)
#pragma unroll
    for (int n = 0; n < 4; n++) acc[m][n] = zz;

#pragma unroll
  for (int q = 0; q < 4; q++) { QST_A(0, q, 0); }
#pragma unroll
  for (int q = 0; q < 4; q++) { QST_B(0, q, 0); }
#pragma unroll
  for (int q = 0; q < 4; q++) { QST_A(1, q, 1); }
#pragma unroll
  for (int q = 0; q < 4; q++) { QST_B(1, q, 1); }
  asm volatile("s_waitcnt vmcnt(8)" ::: "memory");
  BAR();

  f16x8 af[4][2], bf[4][2];
#pragma unroll 2
  for (int t = 0; t < 12; ++t) {
    int c = t & 1;
    const char* ab = (const char*)lds + c * 32768;
    const char* bb = ab + 16384;
    int rA = wr * 64 + l16;
    int rB = wc * 64 + l16;
#pragma unroll
    for (int mf = 0; mf < 4; mf++) {
      af[mf][0] = *(const f16x8*)(ab + (rA + mf * 16) * 128 + cb0);
      af[mf][1] = *(const f16x8*)(ab + (rA + mf * 16) * 128 + cb1);
    }
#pragma unroll
    for (int nf = 0; nf < 4; nf++) {
      bf[nf][0] = *(const f16x8*)(bb + (rB + nf * 16) * 128 + cb0);
      bf[nf][1] = *(const f16x8*)(bb + (rB + nf * 16) * 128 + cb1);
    }
    asm volatile("s_waitcnt lgkmcnt(0)" ::: "memory");
    BAR();
    if (t < 10) {
#pragma unroll
      for (int q = 0; q < 4; q++) { QST_A(c, q, t + 2); }
#pragma unroll
      for (int q = 0; q < 4; q++) { QST_B(c, q, t + 2); }
    }
    __builtin_amdgcn_s_setprio(1);
#pragma unroll
    for (int ks = 0; ks < 2; ks++)
#pragma unroll
      for (int mf = 0; mf < 4; mf++)
#pragma unroll
        for (int nf = 0; nf < 4; nf++)
          acc[mf][nf] = mm(af[mf][ks], bf[nf][ks], acc[mf][nf]);
    __builtin_amdgcn_s_setprio(0);
    if (t < 10) asm volatile("s_waitcnt vmcnt(8)" ::: "memory");
    else        asm volatile("s_waitcnt vmcnt(0)" ::: "memory");
    BAR();
  }

  // ---- coalesced LDS epilogue (32KB [128][128] C-tile) ----
  int s  = bn / 6;
  int h0 = (bn % 6) * 2;
  size_t comp;
  if (s == 0) comp = 0; else if (s == 1) comp = 1; else if (s == 2) comp = 3;
  else if (s == 3) comp = 4; else if (s == 4) comp = 2; else comp = 5;
  int g = (bm * 128) >> 12;
  size_t base = comp * cstr + (size_t)g * S3;
  int n0 = (bm & 31) * 8;

  __syncthreads();
#pragma unroll
  for (int mi = 0; mi < 4; mi++)
#pragma unroll
    for (int ni = 0; ni < 4; ni++)
#pragma unroll
      for (int r = 0; r < 4; r++) {
        int t = wr * 64 + mi * 16 + lq * 4 + r;
        int col = wc * 64 + ni * 16 + l16;
        lds[esw(t, col)] = (f16)acc[mi][ni][r];
      }
  __syncthreads();

  if (s < 2) {            // qc/kc [h][n][c][d]
#pragma unroll
    for (int i = 0; i < 4; i++) {
      int u = wave * 4 + i;
      int hl = u >> 3, j16 = u & 7;
#pragma unroll
      for (int half = 0; half < 2; half++) {
        int e0 = half * 512 + lane * 8;
        int cc = e0 >> 6, d0 = e0 & 63;
        f16x8 v = *(const f16x8*)&lds[esw(j16 * 16 + cc, hl * 64 + d0)];
        __builtin_nontemporal_store(v, (f16x8*)&area[base +
            (size_t)(h0 + hl) * 262144 + (size_t)(n0 + j16) * 1024 + e0]);
      }
    }
  } else if (s < 4) {     // qs/ks [h][c][n][d]
#pragma unroll
    for (int i = 0; i < 8; i++) {
      int u = wave * 8 + i;
      int hl = u >> 4, cc = u & 15;
      int e = lane * 8;
      int nl = e >> 6, d0 = e & 63;
      f16x8 v = *(const f16x8*)&lds[esw(nl * 16 + cc, hl * 64 + d0)];
      __builtin_nontemporal_store(v, (f16x8*)&area[base +
          (size_t)((h0 + hl) * 16 + cc) * 16384 + (size_t)n0 * 64 + e]);
    }
  } else if (s == 4) {    // vc [h][n][d][c]
#pragma unroll
    for (int i = 0; i < 4; i++) {
      int u = wave * 4 + i;
      int hl = u >> 3, j8 = u & 7;
#pragma unroll
      for (int half = 0; half < 2; half++) {
        int e0 = half * 512 + lane * 8;
        int d0 = e0 >> 4, cb = e0 & 15;
        f16x8 v;
#pragma unroll
        for (int j = 0; j < 8; j++)
          v[j] = lds[esw(j8 * 16 + cb + j, hl * 64 + d0)];
        __builtin_nontemporal_store(v, (f16x8*)&area[base +
            (size_t)((h0 + hl) * 256 + n0 + j8) * 1024 + e0]);
      }
    }
  } else {                // vs blocked [h][c][nb8][d][nl8]
#pragma unroll
    for (int i = 0; i < 8; i++) {
      int u = wave * 8 + i;
      int hl = u >> 4, cc = u & 15;
      int e = lane * 8;
      int d0 = e >> 3;
      f16x8 v;
#pragma unroll
      for (int j = 0; j < 8; j++)
        v[j] = lds[esw(j * 16 + cc, hl * 64 + d0)];
      __builtin_nontemporal_store(v, (f16x8*)&area[base +
          ((size_t)((h0 + hl) * 16 + cc) * 32 + (bm & 31)) * 512 + e]);
    }
  }
}

// ---------- proj GEMM: 128x128 tile, same pipeline, out = A*wpt^T + bias ----
__global__ __launch_bounds__(256, 2) void gemm_projT(
    const f16* __restrict__ A,       // prod [G*4096][768] (comp6)
    const f16* __restrict__ Bt,      // wpt [768][768]
    const float* __restrict__ bias, float* __restrict__ Cout) {
  __shared__ f16 lds[32768];
  int id  = blockIdx.x;
  int cpx = gridDim.x >> 3;
  int id2 = (id & 7) * cpx + (id >> 3);       // grid = G*192, %8==0
  int sr = id2 / 48, rr = id2 % 48;
  int bm = sr * 8 + (rr & 7), bn = rr >> 3;   // bm 0..G*32-1, bn 0..5

  int tid = threadIdx.x;
  int wave = tid >> 6, lane = tid & 63;
  int l16 = lane & 15, lq = lane >> 4;
  int wr = wave >> 1, wc = wave & 1;
  int l7 = l16 & 7;
  int cb0 = ((lq) ^ l7) << 4;
  int cb1 = ((4 + lq) ^ l7) << 4;

  const f16* aSrc = A  + (size_t)(bm * 128 + (tid >> 3)) * 768 +
                    (((tid & 7) ^ ((tid >> 3) & 7)) << 3);
  const f16* bSrc = Bt + (size_t)(bn * 128 + (tid >> 3)) * 768 +
                    (((tid & 7) ^ ((tid >> 3) & 7)) << 3);

  f32x4 zz = {0.f, 0.f, 0.f, 0.f};
  f32x4 acc[4][4];
#pragma unroll
  for (int m = 0; m < 4; m++)
#pragma unroll
    for (int n = 0; n < 4; n++) acc[m][n] = zz;

#pragma unroll
  for (int q = 0; q < 4; q++) { QST_A(0, q, 0); }
#pragma unroll
  for (int q = 0; q < 4; q++) { QST_B(0, q, 0); }
#pragma unroll
  for (int q = 0; q < 4; q++) { QST_A(1, q, 1); }
#pragma unroll
  for (int q = 0; q < 4; q++) { QST_B(1, q, 1); }
  asm volatile("s_waitcnt vmcnt(8)" ::: "memory");
  BAR();

  f16x8 af[4][2], bf[4][2];
#pragma unroll 2
  for (int t = 0; t < 12; ++t) {
    int c = t & 1;
    const char* ab = (const char*)lds + c * 32768;
    const char* bb = ab + 16384;
    int rA = wr * 64 + l16;
    int rB = wc * 64 + l16;
#pragma unroll
    for (int mf = 0; mf < 4; mf++) {
      af[mf][0] = *(const f16x8*)(ab + (rA + mf * 16) * 128 + cb0);
      af[mf][1] = *(const f16x8*)(ab + (rA + mf * 16) * 128 + cb1);
    }
#pragma unroll
    for (int nf = 0; nf < 4; nf++) {
      bf[nf][0] = *(const f16x8*)(bb + (rB + nf * 16) * 128 + cb0);
      bf[nf][1] = *(const f16x8*)(bb + (rB + nf * 16) * 128 + cb1);
    }
    asm volatile("s_waitcnt lgkmcnt(0)" ::: "memory");
    BAR();
    if (t < 10) {
#pragma unroll
      for (int q = 0; q < 4; q++) { QST_A(c, q, t + 2); }
#pragma unroll
      for (int q = 0; q < 4; q++) { QST_B(c, q, t + 2); }
    }
    __builtin_amdgcn_s_setprio(1);
#pragma unroll
    for (int ks = 0; ks < 2; ks++)
#pragma unroll
      for (int mf = 0; mf < 4; mf++)
#pragma unroll
        for (int nf = 0; nf < 4; nf++)
          acc[mf][nf] = mm(af[mf][ks], bf[nf][ks], acc[mf][nf]);
    __builtin_amdgcn_s_setprio(0);
    if (t < 10) asm volatile("s_waitcnt vmcnt(8)" ::: "memory");
    else        asm volatile("s_waitcnt vmcnt(0)" ::: "memory");
    BAR();
  }

  // direct fp32 epilogue with bias
#pragma unroll
  for (int ni = 0; ni < 4; ni++) {
    int col = bn * 128 + wc * 64 + ni * 16 + l16;
    float bb = bias[col];
#pragma unroll
    for (int mi = 0; mi < 4; mi++) {
#pragma unroll
      for (int r = 0; r < 4; r++) {
        int row = bm * 128 + wr * 64 + mi * 16 + lq * 4 + r;
        __builtin_nontemporal_store(acc[mi][ni][r] + bb,
                                    &Cout[(size_t)row * 768 + col]);
      }
    }
  }
}

// ---------------- channel attention: per (g,n); xc OUT = [n][h][c][d] -------
// Runs BEFORE spat now. Writes pure xc (no combine) to comp6 (x16 dead).
__global__ __launch_bounds__(256) void attn_chan_kernel(f16* __restrict__ area,
                                                        long long cstr_) {
  size_t cstr = (size_t)cstr_;
  int blk = blockIdx.x;
  int g = blk >> 8, n = blk & 255;
  size_t goff = (size_t)g * S3;
  int tid = threadIdx.x;
  int wave = tid >> 6, lane = tid & 63;
  int l16 = lane & 15, lq = lane >> 4;
  __shared__ f16 prl[12288];
  __shared__ f16 plds[4][16][40];

  if (lane < 16) {
#pragma unroll
    for (int j = 0; j < 16; j++) plds[wave][lane][16 + j] = (f16)0.f;  // zero K-pad
  }
  __syncthreads();

  f32x4 zz = {0.f, 0.f, 0.f, 0.f};
  for (int hi = 0; hi < 3; hi++) {
    int h = wave + hi * 4;
    const f16* q = area + 0 * cstr + goff + (size_t)((h * 256 + n) * 16) * 64;
    const f16* k = area + 1 * cstr + goff + (size_t)((h * 256 + n) * 16) * 64;
    const f16* v = area + 2 * cstr + goff + (size_t)((h * 256 + n) * 64) * 16; // [d][c]
    f16x8 a0 = *(const f16x8*)&q[l16 * 64 + lq * 8];
    f16x8 a1 = *(const f16x8*)&q[l16 * 64 + 32 + lq * 8];
    f16x8 b0 = *(const f16x8*)&k[l16 * 64 + lq * 8];
    f16x8 b1 = *(const f16x8*)&k[l16 * 64 + 32 + lq * 8];
    f32x4 s = mm(a1, b1, mm(a0, b0, zz));
    float p[4];
#pragma unroll
    for (int r = 0; r < 4; r++) {
      float t = s[r] * 0.125f;
      float mx = t;
      mx = fmaxf(mx, __shfl_xor(mx, 1));
      mx = fmaxf(mx, __shfl_xor(mx, 2));
      mx = fmaxf(mx, __shfl_xor(mx, 4));
      mx = fmaxf(mx, __shfl_xor(mx, 8));
      float e = __expf(t - mx);
      float sum = e;
      sum += __shfl_xor(sum, 1);
      sum += __shfl_xor(sum, 2);
      sum += __shfl_xor(sum, 4);
      sum += __shfl_xor(sum, 8);
      p[r] = e / sum;
    }
#pragma unroll
    for (int r = 0; r < 4; r++)
      plds[wave][lq * 4 + r][l16] = (f16)p[r];
    f16x8 ap = *(const f16x8*)&plds[wave][l16][lq * 8]; // k>=16 are zeros
#pragma unroll
    for (int nt = 0; nt < 4; nt++) {
      f16x8 bv = *(const f16x8*)&v[(nt * 16 + l16) * 16 + lq * 8];
      f32x4 o = mm(ap, bv, zz);
#pragma unroll
      for (int r = 0; r < 4; r++) {
        int cq = lq * 4 + r, d = nt * 16 + l16;
        prl[h * 1024 + cq * 64 + d] = (f16)o[r];
      }
    }
  }
  __syncthreads();
  f16* xc = area + 6 * cstr + goff + (size_t)n * 12288;
#pragma unroll
  for (int i = 0; i < 6; i++) {
    f16x8 v = *(const f16x8*)&prl[i * 2048 + tid * 8];
    __builtin_nontemporal_store(v, (f16x8*)&xc[i * 2048 + tid * 8]);
  }
}

// ---------------- spatial attention + combine: per (g,h,c) ------------------
// Epilogue: prod = O * xc written IN-PLACE over xc (comp6, [n][h][c][d]).
// T13 defer-max on the online softmax.
__global__ __launch_bounds__(512) void attn_spat_kernel(f16* __restrict__ area,
                                                        long long cstr_) {
  size_t cstr = (size_t)cstr_;
  int blk = blockIdx.x;
  int g = blk / 192, rem = blk % 192;
  int h = rem >> 4, c = rem & 15;
  size_t goff = (size_t)g * S3;
  const f16* qs = area + 3 * cstr + goff + (size_t)((h * 16 + c) * 256) * 64;
  const f16* ks = area + 4 * cstr + goff + (size_t)((h * 16 + c) * 256) * 64;
  const f16* vsb = area + 5 * cstr + goff + (size_t)(h * 16 + c) * 16384; // [nb8][d][nl8]
  f16* xcn = area + 6 * cstr + goff;   // xc in / prod out, [n][h][c][d]

  int tid = threadIdx.x;
  int wave = tid >> 6, lane = tid & 63;
  int l16 = lane & 15, lq = lane >> 4;
  __shared__ f16 plds[8][32][40];
  __shared__ f16 osm[16384];          // [256][64] swizzled (oesw)

  f32x4 zz = {0.f, 0.f, 0.f, 0.f};
  f16x8 aq[2][2];
#pragma unroll
  for (int m = 0; m < 2; m++)
#pragma unroll
    for (int kd = 0; kd < 2; kd++)
      aq[m][kd] = *(const f16x8*)&qs[(size_t)(wave * 32 + m * 16 + l16) * 64 + kd * 32 + lq * 8];

  f32x4 o[2][4];
  float mrow[2][4], lrow[2][4];
#pragma unroll
  for (int m = 0; m < 2; m++) {
#pragma unroll
    for (int n = 0; n < 4; n++) o[m][n] = zz;
#pragma unroll
    for (int r = 0; r < 4; r++) { mrow[m][r] = -1e30f; lrow[m][r] = 0.f; }
  }

  for (int kc = 0; kc < 8; kc++) {
    int k0 = kc * 32;
    f16x8 bk00 = *(const f16x8*)&ks[(size_t)(k0 + l16) * 64 + lq * 8];
    f16x8 bk01 = *(const f16x8*)&ks[(size_t)(k0 + l16) * 64 + 32 + lq * 8];
    f16x8 bk10 = *(const f16x8*)&ks[(size_t)(k0 + 16 + l16) * 64 + lq * 8];
    f16x8 bk11 = *(const f16x8*)&ks[(size_t)(k0 + 16 + l16) * 64 + 32 + lq * 8];
    f32x4 st[2][2];
#pragma unroll
    for (int m = 0; m < 2; m++) {
      st[m][0] = mm(aq[m][1], bk01, mm(aq[m][0], bk00, zz));
      st[m][1] = mm(aq[m][1], bk11, mm(aq[m][0], bk10, zz));
    }
#pragma unroll
    for (int m = 0; m < 2; m++) {
#pragma unroll
      for (int r = 0; r < 4; r++) {
        float s0 = st[m][0][r] * 0.125f, s1 = st[m][1][r] * 0.125f;
        float t = fmaxf(s0, s1);
        t = fmaxf(t, __shfl_xor(t, 1));
        t = fmaxf(t, __shfl_xor(t, 2));
        t = fmaxf(t, __shfl_xor(t, 4));
        t = fmaxf(t, __shfl_xor(t, 8));
        float mold = mrow[m][r];
        if (!__all(t - mold <= 8.f)) {   // defer-max
          float mnew = fmaxf(mold, t);
          float fac  = __expf(mold - mnew);
          mrow[m][r] = mnew;
          lrow[m][r] *= fac;
          o[m][0][r] *= fac; o[m][1][r] *= fac; o[m][2][r] *= fac; o[m][3][r] *= fac;
          mold = mnew;
        }
        float p0 = __expf(s0 - mold), p1 = __expf(s1 - mold);
        lrow[m][r] += p0 + p1;
        int prow = m * 16 + lq * 4 + r;
        plds[wave][prow][l16]      = (f16)p0;
        plds[wave][prow][16 + l16] = (f16)p1;
      }
    }
    f16x8 ap0 = *(const f16x8*)&plds[wave][l16][lq * 8];
    f16x8 ap1 = *(const f16x8*)&plds[wave][16 + l16][lq * 8];
#pragma unroll
    for (int n = 0; n < 4; n++) {
      f16x8 bv = *(const f16x8*)&vsb[((k0 >> 3) + lq) * 512 + (n * 16 + l16) * 8];
      o[0][n] = mm(ap0, bv, o[0][n]);
      o[1][n] = mm(ap1, bv, o[1][n]);
    }
  }
#pragma unroll
  for (int m = 0; m < 2; m++)
#pragma unroll
    for (int r = 0; r < 4; r++) {
      float l = lrow[m][r];
      l += __shfl_xor(l, 1);
      l += __shfl_xor(l, 2);
      l += __shfl_xor(l, 4);
      l += __shfl_xor(l, 8);
      lrow[m][r] = 1.0f / l;
    }
#pragma unroll
  for (int m = 0; m < 2; m++)
#pragma unroll
    for (int n = 0; n < 4; n++)
#pragma unroll
      for (int r = 0; r < 4; r++) {
        int row = wave * 32 + m * 16 + lq * 4 + r;
        osm[oesw(row, n * 16 + l16)] = (f16)(o[m][n][r] * lrow[m][r]);
      }
  __syncthreads();
  size_t hc64 = (size_t)(h * 16 + c) * 64;
#pragma unroll
  for (int i = 0; i < 4; i++) {
    int row = i * 64 + (tid >> 3);
    int dp  = (tid & 7) * 8;
    size_t dst = (size_t)row * 12288 + hc64 + dp;
    f16x8 v   = *(const f16x8*)&osm[oesw(row, dp)];
    f16x8 xcv = *(const f16x8*)&xcn[dst];
    f16x8 pv;
#pragma unroll
    for (int j = 0; j < 8; j++)
      pv[j] = (f16)((float)v[j] * (float)xcv[j]);
    __builtin_nontemporal_store(pv, (f16x8*)&xcn[dst]);
  }
}

// ---------------- host ------------------------------------------------------
extern "C" void kernel_launch(void* const* d_in, const int* in_sizes, int n_in,
                              void* d_out, int out_size, void* d_ws, size_t ws_size,
                              hipStream_t stream) {
  const float* x      = (const float*)d_in[0];
  const float* w_qkv  = (const float*)d_in[1];
  const float* w_proj = (const float*)d_in[2];
  const float* b_proj = (const float*)d_in[3];
  float* out = (float*)d_out;
  f16* ws = (f16*)d_ws;

  const size_t W16T = 4608ull * 768;
  const size_t WPT  = 768ull * 768;
  f16* w16t = ws;
  f16* wpt  = ws + W16T;
  f16* area = wpt + WPT;

  // 7-component plan: 0 qc, 1 kc, 2 vc, 3 qs, 4 ks, 5 vs, 6 x16->xc->prod
  int G = 8;  // batches per chunk; shrink until scratch fits
  while (G > 1 && (W16T + WPT + 7ull * G * S3) * 2 > ws_size) G >>= 1;
  int nch = 8 / G;
  long long cstr = (long long)G * S3;
  f16* x16 = area + 6 * (size_t)cstr;

  cvt_T_kernel<<<dim3(144, 24), 256, 0, stream>>>(w_qkv, w16t, 768, 4608);
  cvt_T_kernel<<<dim3(24, 24), 256, 0, stream>>>(w_proj, wpt, 768, 768);

  for (int ch = 0; ch < nch; ch++) {
    size_t b0 = (size_t)ch * G;
    cvt_x_kernel<<<G * 1536, 256, 0, stream>>>(x + b0 * S3, x16);
    gemm_qkvT<<<G * 1152, 256, 0, stream>>>(x16, w16t, area, cstr);
    attn_chan_kernel<<<G * 256, 256, 0, stream>>>(area, cstr);   // xc -> comp6
    attn_spat_kernel<<<G * 192, 512, 0, stream>>>(area, cstr);   // prod in-place
    gemm_projT<<<G * 192, 256, 0, stream>>>(area + 6 * (size_t)cstr, wpt, b_proj,
                                            out + b0 * S3);
  }
}